// Round 1
// baseline (3171.092 us; speedup 1.0000x reference)
//
#include <hip/hip_runtime.h>
#include <hip/hip_bf16.h>

#define B_ 4
#define N_ 2048
#define D_ 1024
#define H_ 16
#define HD_ 64
#define MTOT (B_*N_)   // 8192

typedef __attribute__((ext_vector_type(8))) short short8v;
typedef __attribute__((ext_vector_type(4))) float f32x4;

// ---------------- cast x -> bf16 (vectorized) ----------------
__global__ void k_cast_bf16(const float* __restrict__ in, __hip_bfloat16* __restrict__ out, int n4){
  int i = blockIdx.x*256 + threadIdx.x;
  if (i >= n4) return;
  float4 vv = ((const float4*)in)[i];
  __hip_bfloat16 b0 = __float2bfloat16(vv.x), b1 = __float2bfloat16(vv.y),
                 b2 = __float2bfloat16(vv.z), b3 = __float2bfloat16(vv.w);
  ushort4 o;
  o.x = *(const unsigned short*)&b0; o.y = *(const unsigned short*)&b1;
  o.z = *(const unsigned short*)&b2; o.w = *(const unsigned short*)&b3;
  ((ushort4*)out)[i] = o;
}

// ---------------- transpose + cast: out[c][r] = in[r][c] ----------------
__global__ void k_transpose_cast(const float* __restrict__ in, __hip_bfloat16* __restrict__ out,
                                 int R, int C){
  __shared__ float tile[64][65];
  int r0 = blockIdx.y*64, c0 = blockIdx.x*64;
  int tid = threadIdx.x;
  #pragma unroll
  for (int i=0;i<16;i++){ int idx = tid + i*256; int rr = idx>>6, cc = idx&63;
    tile[rr][cc] = in[(size_t)(r0+rr)*C + (c0+cc)]; }
  __syncthreads();
  #pragma unroll
  for (int i=0;i<16;i++){ int idx = tid + i*256; int rr = idx>>6, cc = idx&63;
    out[(size_t)(c0+rr)*R + (r0+cc)] = __float2bfloat16(tile[cc][rr]); }
}

// ---------------- small projections: t1 = x@Wg1 (bf16), lr = 0.01*sigmoid(x@Wlr) ----------------
__global__ __launch_bounds__(256) void k_small_proj(const float* __restrict__ x,
    const float* __restrict__ Wg1, const float* __restrict__ Wlr,
    __hip_bfloat16* __restrict__ t1, float* __restrict__ lrout)
{
  __shared__ float xs[1024];
  __shared__ float red[256];
  int m = blockIdx.x, tid = threadIdx.x;
  for (int i=tid;i<1024;i+=256) xs[i] = x[(size_t)m*1024 + i];
  __syncthreads();
  int j = tid & 63, pp = tid >> 6;
  float acc = 0.f;
  for (int kk = pp*256; kk < pp*256+256; ++kk) acc = fmaf(xs[kk], Wg1[(size_t)kk*64 + j], acc);
  red[tid] = acc; __syncthreads();
  if (tid < 64) t1[(size_t)m*64 + tid] =
      __float2bfloat16(red[tid] + red[tid+64] + red[tid+128] + red[tid+192]);
  __syncthreads();
  int hh = tid & 15, p2 = tid >> 4;
  float a2 = 0.f;
  for (int kk = p2*64; kk < p2*64+64; ++kk) a2 = fmaf(xs[kk], Wlr[(size_t)kk*16 + hh], a2);
  red[tid] = a2; __syncthreads();
  if (tid < 16){
    float s = 0.f;
    #pragma unroll
    for (int p3=0;p3<16;p3++) s += red[hh + p3*16];
    lrout[(size_t)m*16 + hh] = 0.01f/(1.0f + __expf(-s));
  }
}

// ---------------- bf16 MFMA GEMM: C = act(A @ BT^T), A:(M,K) BT:(N,K) bf16, C fp32 ----------------
// ACT: 0 none, 1 silu.  LAYOUT: 0 -> C[m*N+col]; 1 -> C[((b*16+h)*2048+t)*64+e] scatter (q/k/v)
template<int ACT, int LAYOUT>
__global__ __launch_bounds__(256,2) void k_gemm_bt(
    const __hip_bfloat16* __restrict__ A, const __hip_bfloat16* __restrict__ BT,
    float* __restrict__ C, int M, int N, int K)
{
  __shared__ short As[128][40];   // +8 pad: breaks 8-way bank conflict on b128 frag reads
  __shared__ short Bs[128][40];
  const int n0 = blockIdx.x*128, m0 = blockIdx.y*128;
  const int tid = threadIdx.x, lane = tid & 63, wid = tid >> 6;
  const int wm = wid >> 1, wn = wid & 1;
  const short* Aps = (const short*)A;
  const short* Bps = (const short*)BT;
  f32x4 acc[4][4] = {};
  const int r = tid >> 2, seg = (tid & 3)*8;
  for (int kk = 0; kk < K; kk += 32) {
    short8v a0 = *(const short8v*)(Aps + (size_t)(m0+r)*K + kk + seg);
    short8v a1 = *(const short8v*)(Aps + (size_t)(m0+r+64)*K + kk + seg);
    short8v b0 = *(const short8v*)(Bps + (size_t)(n0+r)*K + kk + seg);
    short8v b1 = *(const short8v*)(Bps + (size_t)(n0+r+64)*K + kk + seg);
    __syncthreads();
    *(short8v*)(&As[r][seg])    = a0;
    *(short8v*)(&As[r+64][seg]) = a1;
    *(short8v*)(&Bs[r][seg])    = b0;
    *(short8v*)(&Bs[r+64][seg]) = b1;
    __syncthreads();
    const int row = lane & 15, kq = (lane >> 4)*8;
    short8v af[4], bfr[4];
    #pragma unroll
    for (int i=0;i<4;i++) af[i]  = *(const short8v*)(&As[wm*64 + i*16 + row][kq]);
    #pragma unroll
    for (int j=0;j<4;j++) bfr[j] = *(const short8v*)(&Bs[wn*64 + j*16 + row][kq]);
    #pragma unroll
    for (int i=0;i<4;i++)
      #pragma unroll
      for (int j=0;j<4;j++)
        acc[i][j] = __builtin_amdgcn_mfma_f32_16x16x32_bf16(af[i], bfr[j], acc[i][j], 0, 0, 0);
  }
  #pragma unroll
  for (int i=0;i<4;i++){
    #pragma unroll
    for (int j=0;j<4;j++){
      int col = n0 + wn*64 + j*16 + (lane & 15);
      #pragma unroll
      for (int qq=0; qq<4; ++qq){
        int rowg = m0 + wm*64 + i*16 + (lane>>4)*4 + qq;
        float val = acc[i][j][qq];
        if (ACT==1) val = val/(1.0f+__expf(-val));
        if (LAYOUT==0) {
          C[(size_t)rowg*N + col] = val;
        } else {
          size_t oidx = ((((size_t)(rowg>>11))*16 + (col>>6))*(size_t)N_ + (size_t)(rowg & 2047))*64
                        + (size_t)(col & 63);
          C[oidx] = val;
        }
      }
    }
  }
}

// ---------------- sequential fast-weight scan: one wave per (b,h) ----------------
__global__ __launch_bounds__(64,1) void k_scan(
    const float* __restrict__ q, const float* __restrict__ k, const float* __restrict__ v,
    const float* __restrict__ lr, const float* __restrict__ w1i, const float* __restrict__ w3i,
    float* __restrict__ so)
{
  const int bh = blockIdx.x;     // b*16+h
  const int b  = bh >> 4;
  const int h  = bh & 15;
  const int e  = threadIdx.x;    // 0..63, lane owns column e of W1/W3
  float w1[64], w3[64];
  const float* w1p = w1i + (size_t)h*HD_*HD_;
  const float* w3p = w3i + (size_t)h*HD_*HD_;
  #pragma unroll
  for (int d=0; d<64; ++d) { w1[d] = w1p[d*64 + e]; w3[d] = w3p[d*64 + e]; }
  const float* kr = k + (size_t)bh*N_*64;   // [b][h][t][e] layout, contiguous per t
  const float* qr = q + (size_t)bh*N_*64;
  const float* vr = v + (size_t)bh*N_*64;
  const float* lrp = lr + h;
  float* sop = so + ((size_t)b*N_*16 + h)*64 + e;   // [b][t][h][e]
  #pragma unroll 1
  for (int t=0; t<N_; ++t) {
    const float vv  = vr[e];
    const float lrt = lrp[(size_t)(b*N_ + t)*16];
    float h1a=0.f,h1b=0.f,h3a=0.f,h3b=0.f;
    #pragma unroll
    for (int d=0; d<64; d+=2) {
      float k0 = kr[d], k1 = kr[d+1];
      h1a = fmaf(k0, w1[d],   h1a);
      h3a = fmaf(k0, w3[d],   h3a);
      h1b = fmaf(k1, w1[d+1], h1b);
      h3b = fmaf(k1, w3[d+1], h3b);
    }
    float h1 = h1a+h1b, h3 = h3a+h3b;
    float sg = 1.0f/(1.0f+__expf(-h1));
    float s1 = h1*sg;                       // silu(h1)
    float er = fmaf(s1, h3, -vv);           // s1*h3 - v
    float ds = sg*fmaf(h1, (1.0f-sg), 1.0f);
    float c1 = lrt*(er*h3*ds);
    float c3 = lrt*(er*s1);
    float o1a=0.f,o1b=0.f,o3a=0.f,o3b=0.f;
    #pragma unroll
    for (int d=0; d<64; d+=2) {
      float k0 = kr[d], k1 = kr[d+1];
      float q0 = qr[d], q1 = qr[d+1];
      w1[d]   = fmaf(-k0, c1, w1[d]);   o1a = fmaf(q0, w1[d],   o1a);
      w3[d]   = fmaf(-k0, c3, w3[d]);   o3a = fmaf(q0, w3[d],   o3a);
      w1[d+1] = fmaf(-k1, c1, w1[d+1]); o1b = fmaf(q1, w1[d+1], o1b);
      w3[d+1] = fmaf(-k1, c3, w3[d+1]); o3b = fmaf(q1, w3[d+1], o3b);
    }
    float o1 = o1a+o1b, o3 = o3a+o3b;
    float outv = (o1/(1.0f+__expf(-o1)))*o3;
    sop[(size_t)t*1024] = outv;             // stride per t = H*HD
    kr += 64; qr += 64; vr += 64;
  }
}

// ---------------- grouped RMSNorm * norm_w * sigmoid(gate) -> bf16 y ----------------
__global__ void k_norm_gate(const float* __restrict__ so, const float* __restrict__ gate,
                            const float* __restrict__ nw, __hip_bfloat16* __restrict__ y)
{
  int idx = blockIdx.x*4 + (threadIdx.x>>6);  // (b*N+t)*16+h
  int e = threadIdx.x & 63;
  float o = so[(size_t)idx*64 + e];
  float ss = o*o;
  #pragma unroll
  for (int m=32; m>=1; m>>=1) ss += __shfl_xor(ss, m, 64);
  float rms = rsqrtf(ss*(1.0f/64.0f) + 1e-6f);
  int hh = idx & 15;
  size_t bn = (size_t)(idx >> 4);
  int d = hh*64 + e;
  float g = gate[bn*1024 + d];
  float val = o*rms*nw[d] * (1.0f/(1.0f+__expf(-g)));
  y[bn*1024 + d] = __float2bfloat16(val);
}

extern "C" void kernel_launch(void* const* d_in, const int* in_sizes, int n_in,
                              void* d_out, int out_size, void* d_ws, size_t ws_size,
                              hipStream_t stream)
{
  const float* x   = (const float*)d_in[0];
  const float* Wq  = (const float*)d_in[1];
  const float* Wk  = (const float*)d_in[2];
  const float* Wv  = (const float*)d_in[3];
  const float* Wo  = (const float*)d_in[4];
  const float* w1i = (const float*)d_in[5];
  const float* w3i = (const float*)d_in[6];
  const float* Wlr = (const float*)d_in[7];
  const float* nw  = (const float*)d_in[8];
  const float* Wg1 = (const float*)d_in[9];
  const float* Wg2 = (const float*)d_in[10];
  float* out = (float*)d_out;

  char* p = (char*)d_ws;
  auto take = [&](size_t bytes)->void*{ void* r = (void*)p; p += (bytes + 255) & ~(size_t)255; return r; };
  __hip_bfloat16* xb   = (__hip_bfloat16*)take((size_t)MTOT*D_*2);
  __hip_bfloat16* Wqt  = (__hip_bfloat16*)take((size_t)D_*D_*2);
  __hip_bfloat16* Wkt  = (__hip_bfloat16*)take((size_t)D_*D_*2);
  __hip_bfloat16* Wvt  = (__hip_bfloat16*)take((size_t)D_*D_*2);
  __hip_bfloat16* Wot  = (__hip_bfloat16*)take((size_t)D_*D_*2);
  __hip_bfloat16* Wg2t = (__hip_bfloat16*)take((size_t)D_*HD_*2);
  __hip_bfloat16* t1b  = (__hip_bfloat16*)take((size_t)MTOT*HD_*2);
  float* qf  = (float*)take((size_t)MTOT*D_*4);
  float* kf  = (float*)take((size_t)MTOT*D_*4);
  float* vf  = (float*)take((size_t)MTOT*D_*4);
  float* lrb = (float*)take((size_t)MTOT*H_*4);
  float* sob = (float*)take((size_t)MTOT*D_*4);
  __hip_bfloat16* yb = (__hip_bfloat16*)take((size_t)MTOT*D_*2);

  k_cast_bf16<<<MTOT*D_/4/256, 256, 0, stream>>>(x, xb, MTOT*D_/4);
  k_transpose_cast<<<dim3(16,16), 256, 0, stream>>>(Wq, Wqt, D_, D_);
  k_transpose_cast<<<dim3(16,16), 256, 0, stream>>>(Wk, Wkt, D_, D_);
  k_transpose_cast<<<dim3(16,16), 256, 0, stream>>>(Wv, Wvt, D_, D_);
  k_transpose_cast<<<dim3(16,16), 256, 0, stream>>>(Wo, Wot, D_, D_);
  k_transpose_cast<<<dim3(16,1),  256, 0, stream>>>(Wg2, Wg2t, HD_, D_);
  k_small_proj<<<MTOT, 256, 0, stream>>>(x, Wg1, Wlr, t1b, lrb);
  // q,k,v projections (silu on q,k), scattered to [b][h][t][e]
  k_gemm_bt<1,1><<<dim3(8,64), 256, 0, stream>>>(xb, Wqt, qf, MTOT, D_, D_);
  k_gemm_bt<1,1><<<dim3(8,64), 256, 0, stream>>>(xb, Wkt, kf, MTOT, D_, D_);
  k_gemm_bt<0,1><<<dim3(8,64), 256, 0, stream>>>(xb, Wvt, vf, MTOT, D_, D_);
  // gate pre-activation into d_out (free scratch until final GEMM)
  k_gemm_bt<0,0><<<dim3(8,64), 256, 0, stream>>>(t1b, Wg2t, out, MTOT, D_, HD_);
  k_scan<<<64, 64, 0, stream>>>(qf, kf, vf, lrb, w1i, w3i, sob);
  k_norm_gate<<<MTOT*H_/4, 256, 0, stream>>>(sob, out, nw, yb);
  k_gemm_bt<0,0><<<dim3(8,64), 256, 0, stream>>>(yb, Wot, out, MTOT, D_, D_);
}

// Round 2
// 1728.476 us; speedup vs baseline: 1.8346x; 1.8346x over previous
//
#include <hip/hip_runtime.h>
#include <hip/hip_bf16.h>

#define B_ 4
#define N_ 2048
#define D_ 1024
#define H_ 16
#define HD_ 64
#define MTOT (B_*N_)   // 8192

typedef __attribute__((ext_vector_type(8))) short short8v;
typedef __attribute__((ext_vector_type(4))) float f32x4;

// ---------------- cast x -> bf16 (vectorized) ----------------
__global__ void k_cast_bf16(const float* __restrict__ in, __hip_bfloat16* __restrict__ out, int n4){
  int i = blockIdx.x*256 + threadIdx.x;
  if (i >= n4) return;
  float4 vv = ((const float4*)in)[i];
  __hip_bfloat16 b0 = __float2bfloat16(vv.x), b1 = __float2bfloat16(vv.y),
                 b2 = __float2bfloat16(vv.z), b3 = __float2bfloat16(vv.w);
  ushort4 o;
  o.x = *(const unsigned short*)&b0; o.y = *(const unsigned short*)&b1;
  o.z = *(const unsigned short*)&b2; o.w = *(const unsigned short*)&b3;
  ((ushort4*)out)[i] = o;
}

// ---------------- transpose + cast: out[c][r] = in[r][c] ----------------
__global__ void k_transpose_cast(const float* __restrict__ in, __hip_bfloat16* __restrict__ out,
                                 int R, int C){
  __shared__ float tile[64][65];
  int r0 = blockIdx.y*64, c0 = blockIdx.x*64;
  int tid = threadIdx.x;
  #pragma unroll
  for (int i=0;i<16;i++){ int idx = tid + i*256; int rr = idx>>6, cc = idx&63;
    tile[rr][cc] = in[(size_t)(r0+rr)*C + (c0+cc)]; }
  __syncthreads();
  #pragma unroll
  for (int i=0;i<16;i++){ int idx = tid + i*256; int rr = idx>>6, cc = idx&63;
    out[(size_t)(c0+rr)*R + (r0+cc)] = __float2bfloat16(tile[cc][rr]); }
}

// ---------------- small projections: t1 = x@Wg1 (bf16), lr = 0.01*sigmoid(x@Wlr) ----------------
__global__ __launch_bounds__(256) void k_small_proj(const float* __restrict__ x,
    const float* __restrict__ Wg1, const float* __restrict__ Wlr,
    __hip_bfloat16* __restrict__ t1, float* __restrict__ lrout)
{
  __shared__ float xs[1024];
  __shared__ float red[256];
  int m = blockIdx.x, tid = threadIdx.x;
  for (int i=tid;i<1024;i+=256) xs[i] = x[(size_t)m*1024 + i];
  __syncthreads();
  int j = tid & 63, pp = tid >> 6;
  float acc = 0.f;
  for (int kk = pp*256; kk < pp*256+256; ++kk) acc = fmaf(xs[kk], Wg1[(size_t)kk*64 + j], acc);
  red[tid] = acc; __syncthreads();
  if (tid < 64) t1[(size_t)m*64 + tid] =
      __float2bfloat16(red[tid] + red[tid+64] + red[tid+128] + red[tid+192]);
  __syncthreads();
  int hh = tid & 15, p2 = tid >> 4;
  float a2 = 0.f;
  for (int kk = p2*64; kk < p2*64+64; ++kk) a2 = fmaf(xs[kk], Wlr[(size_t)kk*16 + hh], a2);
  red[tid] = a2; __syncthreads();
  if (tid < 16){
    float s = 0.f;
    #pragma unroll
    for (int p3=0;p3<16;p3++) s += red[hh + p3*16];
    lrout[(size_t)m*16 + hh] = 0.01f/(1.0f + __expf(-s));
  }
}

// ---------------- bf16 MFMA GEMM: C = act(A @ BT^T), A:(M,K) BT:(N,K) bf16, C fp32 ----------------
// ACT: 0 none, 1 silu.  LAYOUT: 0 -> C[m*N+col]; 1 -> C[((b*16+h)*2048+t)*64+e] scatter (q/k/v)
template<int ACT, int LAYOUT>
__global__ __launch_bounds__(256,2) void k_gemm_bt(
    const __hip_bfloat16* __restrict__ A, const __hip_bfloat16* __restrict__ BT,
    float* __restrict__ C, int M, int N, int K)
{
  __shared__ short As[128][40];   // +8 pad: breaks 8-way bank conflict on b128 frag reads
  __shared__ short Bs[128][40];
  const int n0 = blockIdx.x*128, m0 = blockIdx.y*128;
  const int tid = threadIdx.x, lane = tid & 63, wid = tid >> 6;
  const int wm = wid >> 1, wn = wid & 1;
  const short* Aps = (const short*)A;
  const short* Bps = (const short*)BT;
  f32x4 acc[4][4] = {};
  const int r = tid >> 2, seg = (tid & 3)*8;
  for (int kk = 0; kk < K; kk += 32) {
    short8v a0 = *(const short8v*)(Aps + (size_t)(m0+r)*K + kk + seg);
    short8v a1 = *(const short8v*)(Aps + (size_t)(m0+r+64)*K + kk + seg);
    short8v b0 = *(const short8v*)(Bps + (size_t)(n0+r)*K + kk + seg);
    short8v b1 = *(const short8v*)(Bps + (size_t)(n0+r+64)*K + kk + seg);
    __syncthreads();
    *(short8v*)(&As[r][seg])    = a0;
    *(short8v*)(&As[r+64][seg]) = a1;
    *(short8v*)(&Bs[r][seg])    = b0;
    *(short8v*)(&Bs[r+64][seg]) = b1;
    __syncthreads();
    const int row = lane & 15, kq = (lane >> 4)*8;
    short8v af[4], bfr[4];
    #pragma unroll
    for (int i=0;i<4;i++) af[i]  = *(const short8v*)(&As[wm*64 + i*16 + row][kq]);
    #pragma unroll
    for (int j=0;j<4;j++) bfr[j] = *(const short8v*)(&Bs[wn*64 + j*16 + row][kq]);
    #pragma unroll
    for (int i=0;i<4;i++)
      #pragma unroll
      for (int j=0;j<4;j++)
        acc[i][j] = __builtin_amdgcn_mfma_f32_16x16x32_bf16(af[i], bfr[j], acc[i][j], 0, 0, 0);
  }
  #pragma unroll
  for (int i=0;i<4;i++){
    #pragma unroll
    for (int j=0;j<4;j++){
      int col = n0 + wn*64 + j*16 + (lane & 15);
      #pragma unroll
      for (int qq=0; qq<4; ++qq){
        int rowg = m0 + wm*64 + i*16 + (lane>>4)*4 + qq;
        float val = acc[i][j][qq];
        if (ACT==1) val = val/(1.0f+__expf(-val));
        if (LAYOUT==0) {
          C[(size_t)rowg*N + col] = val;
        } else {
          size_t oidx = ((((size_t)(rowg>>11))*16 + (col>>6))*(size_t)N_ + (size_t)(rowg & 2047))*64
                        + (size_t)(col & 63);
          C[oidx] = val;
        }
      }
    }
  }
}

// ---------------- fast-weight scan, column-parallel ----------------
// The recurrence is independent per output column e: state = W1[:,e], W3[:,e].
// 16 lanes per column (lane owns 4 rows -> float4 state in registers),
// 4 columns per wave, 4 waves per block, 4 blocks per (b,h). 1024 waves total.
__global__ __launch_bounds__(256,1) void k_scan2(
    const float* __restrict__ q, const float* __restrict__ k, const float* __restrict__ v,
    const float* __restrict__ lr, const float* __restrict__ w1i, const float* __restrict__ w3i,
    float* __restrict__ so)
{
  const int blk = blockIdx.x;      // 0..255
  const int bh  = blk >> 2;        // b*16+h
  const int jb  = blk & 3;         // which 16-column slab of this bh
  const int b = bh >> 4, h = bh & 15;
  const int tid = threadIdx.x;
  const int g = tid >> 4;          // column group within block: 0..15
  const int l = tid & 15;          // lane within group; owns rows 4l..4l+3
  const int e = jb*16 + g;         // output column

  // init state: W[d][e] at wi[h][d][e], stride 64 per d
  const float* w1p = w1i + (size_t)h*HD_*HD_ + e;
  const float* w3p = w3i + (size_t)h*HD_*HD_ + e;
  float4 w1, w3;
  w1.x = w1p[(4*l+0)*64]; w1.y = w1p[(4*l+1)*64]; w1.z = w1p[(4*l+2)*64]; w1.w = w1p[(4*l+3)*64];
  w3.x = w3p[(4*l+0)*64]; w3.y = w3p[(4*l+1)*64]; w3.z = w3p[(4*l+2)*64]; w3.w = w3p[(4*l+3)*64];

  const float* kr = k + (size_t)bh*N_*64 + 4*l;   // [b][h][t][d]
  const float* qr = q + (size_t)bh*N_*64 + 4*l;
  const float* vp = v + (size_t)bh*N_*64 + e;
  const float* lrp = lr + (size_t)b*N_*16 + h;
  float* sop = so + ((size_t)b*N_*16 + h)*64 + e;  // [b][t][h][e]

  #pragma unroll 1
  for (int t = 0; t < N_; ++t) {
    const float4 k4 = *(const float4*)kr;
    const float4 q4 = *(const float4*)qr;
    const float vv  = *vp;
    const float lrt = *lrp;

    float h1 = fmaf(k4.x, w1.x, fmaf(k4.y, w1.y, fmaf(k4.z, w1.z, k4.w*w1.w)));
    float h3 = fmaf(k4.x, w3.x, fmaf(k4.y, w3.y, fmaf(k4.z, w3.z, k4.w*w3.w)));
    #pragma unroll
    for (int m = 1; m < 16; m <<= 1) { h1 += __shfl_xor(h1, m, 64); h3 += __shfl_xor(h3, m, 64); }

    const float sg = 1.0f/(1.0f + __expf(-h1));
    const float s1 = h1*sg;                    // silu(h1)
    const float er = fmaf(s1, h3, -vv);        // f(k)-v
    const float ds = sg*fmaf(h1, 1.0f - sg, 1.0f);
    const float c1 = lrt*(er*h3*ds);
    const float c3 = lrt*(er*s1);

    w1.x = fmaf(-k4.x, c1, w1.x); w1.y = fmaf(-k4.y, c1, w1.y);
    w1.z = fmaf(-k4.z, c1, w1.z); w1.w = fmaf(-k4.w, c1, w1.w);
    w3.x = fmaf(-k4.x, c3, w3.x); w3.y = fmaf(-k4.y, c3, w3.y);
    w3.z = fmaf(-k4.z, c3, w3.z); w3.w = fmaf(-k4.w, c3, w3.w);

    float o1 = fmaf(q4.x, w1.x, fmaf(q4.y, w1.y, fmaf(q4.z, w1.z, q4.w*w1.w)));
    float o3 = fmaf(q4.x, w3.x, fmaf(q4.y, w3.y, fmaf(q4.z, w3.z, q4.w*w3.w)));
    #pragma unroll
    for (int m = 1; m < 16; m <<= 1) { o1 += __shfl_xor(o1, m, 64); o3 += __shfl_xor(o3, m, 64); }

    if (l == 0) {
      const float outv = (o1/(1.0f + __expf(-o1)))*o3;
      sop[(size_t)t*(H_*HD_)] = outv;
    }
    kr += 64; qr += 64; vp += 64; lrp += 16;
  }
}

// ---------------- grouped RMSNorm * norm_w * sigmoid(gate) -> bf16 y ----------------
__global__ void k_norm_gate(const float* __restrict__ so, const float* __restrict__ gate,
                            const float* __restrict__ nw, __hip_bfloat16* __restrict__ y)
{
  int idx = blockIdx.x*4 + (threadIdx.x>>6);  // (b*N+t)*16+h
  int e = threadIdx.x & 63;
  float o = so[(size_t)idx*64 + e];
  float ss = o*o;
  #pragma unroll
  for (int m=32; m>=1; m>>=1) ss += __shfl_xor(ss, m, 64);
  float rms = rsqrtf(ss*(1.0f/64.0f) + 1e-6f);
  int hh = idx & 15;
  size_t bn = (size_t)(idx >> 4);
  int d = hh*64 + e;
  float g = gate[bn*1024 + d];
  float val = o*rms*nw[d] * (1.0f/(1.0f+__expf(-g)));
  y[bn*1024 + d] = __float2bfloat16(val);
}

extern "C" void kernel_launch(void* const* d_in, const int* in_sizes, int n_in,
                              void* d_out, int out_size, void* d_ws, size_t ws_size,
                              hipStream_t stream)
{
  const float* x   = (const float*)d_in[0];
  const float* Wq  = (const float*)d_in[1];
  const float* Wk  = (const float*)d_in[2];
  const float* Wv  = (const float*)d_in[3];
  const float* Wo  = (const float*)d_in[4];
  const float* w1i = (const float*)d_in[5];
  const float* w3i = (const float*)d_in[6];
  const float* Wlr = (const float*)d_in[7];
  const float* nw  = (const float*)d_in[8];
  const float* Wg1 = (const float*)d_in[9];
  const float* Wg2 = (const float*)d_in[10];
  float* out = (float*)d_out;

  char* p = (char*)d_ws;
  auto take = [&](size_t bytes)->void*{ void* r = (void*)p; p += (bytes + 255) & ~(size_t)255; return r; };
  __hip_bfloat16* xb   = (__hip_bfloat16*)take((size_t)MTOT*D_*2);
  __hip_bfloat16* Wqt  = (__hip_bfloat16*)take((size_t)D_*D_*2);
  __hip_bfloat16* Wkt  = (__hip_bfloat16*)take((size_t)D_*D_*2);
  __hip_bfloat16* Wvt  = (__hip_bfloat16*)take((size_t)D_*D_*2);
  __hip_bfloat16* Wot  = (__hip_bfloat16*)take((size_t)D_*D_*2);
  __hip_bfloat16* Wg2t = (__hip_bfloat16*)take((size_t)D_*HD_*2);
  __hip_bfloat16* t1b  = (__hip_bfloat16*)take((size_t)MTOT*HD_*2);
  float* qf  = (float*)take((size_t)MTOT*D_*4);
  float* kf  = (float*)take((size_t)MTOT*D_*4);
  float* vf  = (float*)take((size_t)MTOT*D_*4);
  float* lrb = (float*)take((size_t)MTOT*H_*4);
  float* sob = (float*)take((size_t)MTOT*D_*4);
  __hip_bfloat16* yb = (__hip_bfloat16*)take((size_t)MTOT*D_*2);

  k_cast_bf16<<<MTOT*D_/4/256, 256, 0, stream>>>(x, xb, MTOT*D_/4);
  k_transpose_cast<<<dim3(16,16), 256, 0, stream>>>(Wq, Wqt, D_, D_);
  k_transpose_cast<<<dim3(16,16), 256, 0, stream>>>(Wk, Wkt, D_, D_);
  k_transpose_cast<<<dim3(16,16), 256, 0, stream>>>(Wv, Wvt, D_, D_);
  k_transpose_cast<<<dim3(16,16), 256, 0, stream>>>(Wo, Wot, D_, D_);
  k_transpose_cast<<<dim3(16,1),  256, 0, stream>>>(Wg2, Wg2t, HD_, D_);
  k_small_proj<<<MTOT, 256, 0, stream>>>(x, Wg1, Wlr, t1b, lrb);
  // q,k,v projections (silu on q,k), scattered to [b][h][t][e]
  k_gemm_bt<1,1><<<dim3(8,64), 256, 0, stream>>>(xb, Wqt, qf, MTOT, D_, D_);
  k_gemm_bt<1,1><<<dim3(8,64), 256, 0, stream>>>(xb, Wkt, kf, MTOT, D_, D_);
  k_gemm_bt<0,1><<<dim3(8,64), 256, 0, stream>>>(xb, Wvt, vf, MTOT, D_, D_);
  // gate pre-activation into d_out (free scratch until final GEMM)
  k_gemm_bt<0,0><<<dim3(8,64), 256, 0, stream>>>(t1b, Wg2t, out, MTOT, D_, HD_);
  k_scan2<<<256, 256, 0, stream>>>(qf, kf, vf, lrb, w1i, w3i, sob);
  k_norm_gate<<<MTOT*H_/4, 256, 0, stream>>>(sob, out, nw, yb);
  k_gemm_bt<0,0><<<dim3(8,64), 256, 0, stream>>>(yb, Wot, out, MTOT, D_, D_);
}

// Round 3
// 1236.389 us; speedup vs baseline: 2.5648x; 1.3980x over previous
//
#include <hip/hip_runtime.h>
#include <hip/hip_bf16.h>

#define B_ 4
#define N_ 2048
#define D_ 1024
#define H_ 16
#define HD_ 64
#define MTOT (B_*N_)   // 8192

typedef __attribute__((ext_vector_type(8))) short short8v;
typedef __attribute__((ext_vector_type(4))) float f32x4;

// ---------------- cast x -> bf16 (vectorized) ----------------
__global__ void k_cast_bf16(const float* __restrict__ in, __hip_bfloat16* __restrict__ out, int n4){
  int i = blockIdx.x*256 + threadIdx.x;
  if (i >= n4) return;
  float4 vv = ((const float4*)in)[i];
  __hip_bfloat16 b0 = __float2bfloat16(vv.x), b1 = __float2bfloat16(vv.y),
                 b2 = __float2bfloat16(vv.z), b3 = __float2bfloat16(vv.w);
  ushort4 o;
  o.x = *(const unsigned short*)&b0; o.y = *(const unsigned short*)&b1;
  o.z = *(const unsigned short*)&b2; o.w = *(const unsigned short*)&b3;
  ((ushort4*)out)[i] = o;
}

// ---------------- transpose + cast: out[c][r] = in[r][c] ----------------
__global__ void k_transpose_cast(const float* __restrict__ in, __hip_bfloat16* __restrict__ out,
                                 int R, int C){
  __shared__ float tile[64][65];
  int r0 = blockIdx.y*64, c0 = blockIdx.x*64;
  int tid = threadIdx.x;
  #pragma unroll
  for (int i=0;i<16;i++){ int idx = tid + i*256; int rr = idx>>6, cc = idx&63;
    tile[rr][cc] = in[(size_t)(r0+rr)*C + (c0+cc)]; }
  __syncthreads();
  #pragma unroll
  for (int i=0;i<16;i++){ int idx = tid + i*256; int rr = idx>>6, cc = idx&63;
    out[(size_t)(c0+rr)*R + (r0+cc)] = __float2bfloat16(tile[cc][rr]); }
}

// ---------------- small projections: t1 = x@Wg1 (bf16), lr = 0.01*sigmoid(x@Wlr) ----------------
__global__ __launch_bounds__(256) void k_small_proj(const float* __restrict__ x,
    const float* __restrict__ Wg1, const float* __restrict__ Wlr,
    __hip_bfloat16* __restrict__ t1, float* __restrict__ lrout)
{
  __shared__ float xs[1024];
  __shared__ float red[256];
  int m = blockIdx.x, tid = threadIdx.x;
  for (int i=tid;i<1024;i+=256) xs[i] = x[(size_t)m*1024 + i];
  __syncthreads();
  int j = tid & 63, pp = tid >> 6;
  float acc = 0.f;
  for (int kk = pp*256; kk < pp*256+256; ++kk) acc = fmaf(xs[kk], Wg1[(size_t)kk*64 + j], acc);
  red[tid] = acc; __syncthreads();
  if (tid < 64) t1[(size_t)m*64 + tid] =
      __float2bfloat16(red[tid] + red[tid+64] + red[tid+128] + red[tid+192]);
  __syncthreads();
  int hh = tid & 15, p2 = tid >> 4;
  float a2 = 0.f;
  for (int kk = p2*64; kk < p2*64+64; ++kk) a2 = fmaf(xs[kk], Wlr[(size_t)kk*16 + hh], a2);
  red[tid] = a2; __syncthreads();
  if (tid < 16){
    float s = 0.f;
    #pragma unroll
    for (int p3=0;p3<16;p3++) s += red[hh + p3*16];
    lrout[(size_t)m*16 + hh] = 0.01f/(1.0f + __expf(-s));
  }
}

// ---------------- bf16 MFMA GEMM: C = act(A @ BT^T), A:(M,K) BT:(N,K) bf16, C fp32 ----------------
// ACT: 0 none, 1 silu.  LAYOUT: 0 -> C[m*N+col]; 1 -> C[((b*16+h)*2048+t)*64+e] scatter (q/k/v)
template<int ACT, int LAYOUT>
__global__ __launch_bounds__(256,2) void k_gemm_bt(
    const __hip_bfloat16* __restrict__ A, const __hip_bfloat16* __restrict__ BT,
    float* __restrict__ C, int M, int N, int K)
{
  __shared__ short As[128][40];   // +8 pad: breaks 8-way bank conflict on b128 frag reads
  __shared__ short Bs[128][40];
  const int n0 = blockIdx.x*128, m0 = blockIdx.y*128;
  const int tid = threadIdx.x, lane = tid & 63, wid = tid >> 6;
  const int wm = wid >> 1, wn = wid & 1;
  const short* Aps = (const short*)A;
  const short* Bps = (const short*)BT;
  f32x4 acc[4][4] = {};
  const int r = tid >> 2, seg = (tid & 3)*8;
  for (int kk = 0; kk < K; kk += 32) {
    short8v a0 = *(const short8v*)(Aps + (size_t)(m0+r)*K + kk + seg);
    short8v a1 = *(const short8v*)(Aps + (size_t)(m0+r+64)*K + kk + seg);
    short8v b0 = *(const short8v*)(Bps + (size_t)(n0+r)*K + kk + seg);
    short8v b1 = *(const short8v*)(Bps + (size_t)(n0+r+64)*K + kk + seg);
    __syncthreads();
    *(short8v*)(&As[r][seg])    = a0;
    *(short8v*)(&As[r+64][seg]) = a1;
    *(short8v*)(&Bs[r][seg])    = b0;
    *(short8v*)(&Bs[r+64][seg]) = b1;
    __syncthreads();
    const int row = lane & 15, kq = (lane >> 4)*8;
    short8v af[4], bfr[4];
    #pragma unroll
    for (int i=0;i<4;i++) af[i]  = *(const short8v*)(&As[wm*64 + i*16 + row][kq]);
    #pragma unroll
    for (int j=0;j<4;j++) bfr[j] = *(const short8v*)(&Bs[wn*64 + j*16 + row][kq]);
    #pragma unroll
    for (int i=0;i<4;i++)
      #pragma unroll
      for (int j=0;j<4;j++)
        acc[i][j] = __builtin_amdgcn_mfma_f32_16x16x32_bf16(af[i], bfr[j], acc[i][j], 0, 0, 0);
  }
  #pragma unroll
  for (int i=0;i<4;i++){
    #pragma unroll
    for (int j=0;j<4;j++){
      int col = n0 + wn*64 + j*16 + (lane & 15);
      #pragma unroll
      for (int qq=0; qq<4; ++qq){
        int rowg = m0 + wm*64 + i*16 + (lane>>4)*4 + qq;
        float val = acc[i][j][qq];
        if (ACT==1) val = val/(1.0f+__expf(-val));
        if (LAYOUT==0) {
          C[(size_t)rowg*N + col] = val;
        } else {
          size_t oidx = ((((size_t)(rowg>>11))*16 + (col>>6))*(size_t)N_ + (size_t)(rowg & 2047))*64
                        + (size_t)(col & 63);
          C[oidx] = val;
        }
      }
    }
  }
}

// ---------------- DPP 16-lane reduction: rotate-and-add within DPP row ----------------
__device__ __forceinline__ float red16(float x){
  int r;
  r = __builtin_amdgcn_update_dpp(0, __float_as_int(x), 0x128, 0xF, 0xF, true); // row_ror:8
  x += __int_as_float(r);
  r = __builtin_amdgcn_update_dpp(0, __float_as_int(x), 0x124, 0xF, 0xF, true); // row_ror:4
  x += __int_as_float(r);
  r = __builtin_amdgcn_update_dpp(0, __float_as_int(x), 0x122, 0xF, 0xF, true); // row_ror:2
  x += __int_as_float(r);
  r = __builtin_amdgcn_update_dpp(0, __float_as_int(x), 0x121, 0xF, 0xF, true); // row_ror:1
  x += __int_as_float(r);
  return x;
}

__device__ __forceinline__ float dot4(const float4 a, const float4 b){
  return fmaf(a.x, b.x, fmaf(a.y, b.y, fmaf(a.z, b.z, a.w*b.w)));
}

// ---------------- fast-weight scan, column-parallel, DPP-reduced, pipelined ----------------
// 16 lanes per column (lane owns 4 rows), 4 cols/wave, 4 waves/block, 4 blocks/(b,h).
// Pipelined: iteration t does activation(t), W-update(t), then o(t) and h(t+1)
// partials+reduces together (both depend only on W^(t)); loads prefetched 2 deep.
__global__ __launch_bounds__(256,1) void k_scan3(
    const float* __restrict__ q, const float* __restrict__ k, const float* __restrict__ v,
    const float* __restrict__ lr, const float* __restrict__ w1i, const float* __restrict__ w3i,
    float* __restrict__ so)
{
  const int blk = blockIdx.x;      // 0..255
  const int bh  = blk >> 2;        // b*16+h
  const int jb  = blk & 3;         // 16-column slab
  const int b = bh >> 4, h = bh & 15;
  const int tid = threadIdx.x;
  const int g = tid >> 4;          // column group (DPP-row aligned)
  const int l = tid & 15;          // lane in group; owns rows 4l..4l+3
  const int e = jb*16 + g;

  const float* w1p = w1i + (size_t)h*HD_*HD_ + e;
  const float* w3p = w3i + (size_t)h*HD_*HD_ + e;
  float4 w1, w3;
  w1.x = w1p[(4*l+0)*64]; w1.y = w1p[(4*l+1)*64]; w1.z = w1p[(4*l+2)*64]; w1.w = w1p[(4*l+3)*64];
  w3.x = w3p[(4*l+0)*64]; w3.y = w3p[(4*l+1)*64]; w3.z = w3p[(4*l+2)*64]; w3.w = w3p[(4*l+3)*64];

  const float* kb = k + (size_t)bh*N_*64 + 4*l;   // [b][h][t][d]
  const float* qb = q + (size_t)bh*N_*64 + 4*l;
  const float* vb = v + (size_t)bh*N_*64 + e;
  const float* lb = lr + (size_t)b*N_*16 + h;
  float* sop = so + ((size_t)b*N_*16 + h)*64 + e;  // [b][t][h][e]

  // prefetch t=0, t=1
  float4 k4  = *(const float4*)(kb);
  float4 q4  = *(const float4*)(qb);
  float  vv  = vb[0];
  float  lt  = lb[0];
  float4 k4n = *(const float4*)(kb + 64);
  float4 q4n = *(const float4*)(qb + 64);
  float  vvn = vb[64];
  float  ltn = lb[16];

  float h1 = red16(dot4(k4, w1));
  float h3 = red16(dot4(k4, w3));

  #pragma unroll 1
  for (int t = 0; t < N_; ++t) {
    // ---- activation / gradient for token t (h1,h3 computed last iteration) ----
    const float sg = 1.0f/(1.0f + __expf(-h1));
    const float s1 = h1*sg;                    // silu(h1)
    const float er = fmaf(s1, h3, -vv);
    const float ds = sg*fmaf(h1, 1.0f - sg, 1.0f);
    const float c1 = lt*(er*h3*ds);
    const float c3 = lt*(er*s1);

    // ---- W update (rank-1) ----
    w1.x = fmaf(-k4.x, c1, w1.x); w1.y = fmaf(-k4.y, c1, w1.y);
    w1.z = fmaf(-k4.z, c1, w1.z); w1.w = fmaf(-k4.w, c1, w1.w);
    w3.x = fmaf(-k4.x, c3, w3.x); w3.y = fmaf(-k4.y, c3, w3.y);
    w3.z = fmaf(-k4.z, c3, w3.z); w3.w = fmaf(-k4.w, c3, w3.w);

    // ---- prefetch t+2 (never on critical path) ----
    const int tn = (t + 2 < N_) ? (t + 2) : (N_ - 1);
    const float4 k4p = *(const float4*)(kb + (size_t)tn*64);
    const float4 q4p = *(const float4*)(qb + (size_t)tn*64);
    const float  vvp = vb[(size_t)tn*64];
    const float  ltp = lb[(size_t)tn*16];

    // ---- o(t) and h(t+1) partials: both depend only on W^(t); reduces interleave ----
    float o1 = red16(dot4(q4,  w1));
    float o3 = red16(dot4(q4,  w3));
    h1       = red16(dot4(k4n, w1));
    h3       = red16(dot4(k4n, w3));

    if (l == 0) {
      sop[(size_t)t*(H_*HD_)] = (o1/(1.0f + __expf(-o1)))*o3;
    }

    k4 = k4n; q4 = q4n; vv = vvn; lt = ltn;
    k4n = k4p; q4n = q4p; vvn = vvp; ltn = ltp;
  }
}

// ---------------- grouped RMSNorm * norm_w * sigmoid(gate) -> bf16 y ----------------
__global__ void k_norm_gate(const float* __restrict__ so, const float* __restrict__ gate,
                            const float* __restrict__ nw, __hip_bfloat16* __restrict__ y)
{
  int idx = blockIdx.x*4 + (threadIdx.x>>6);  // (b*N+t)*16+h
  int e = threadIdx.x & 63;
  float o = so[(size_t)idx*64 + e];
  float ss = o*o;
  #pragma unroll
  for (int m=32; m>=1; m>>=1) ss += __shfl_xor(ss, m, 64);
  float rms = rsqrtf(ss*(1.0f/64.0f) + 1e-6f);
  int hh = idx & 15;
  size_t bn = (size_t)(idx >> 4);
  int d = hh*64 + e;
  float g = gate[bn*1024 + d];
  float val = o*rms*nw[d] * (1.0f/(1.0f+__expf(-g)));
  y[bn*1024 + d] = __float2bfloat16(val);
}

extern "C" void kernel_launch(void* const* d_in, const int* in_sizes, int n_in,
                              void* d_out, int out_size, void* d_ws, size_t ws_size,
                              hipStream_t stream)
{
  const float* x   = (const float*)d_in[0];
  const float* Wq  = (const float*)d_in[1];
  const float* Wk  = (const float*)d_in[2];
  const float* Wv  = (const float*)d_in[3];
  const float* Wo  = (const float*)d_in[4];
  const float* w1i = (const float*)d_in[5];
  const float* w3i = (const float*)d_in[6];
  const float* Wlr = (const float*)d_in[7];
  const float* nw  = (const float*)d_in[8];
  const float* Wg1 = (const float*)d_in[9];
  const float* Wg2 = (const float*)d_in[10];
  float* out = (float*)d_out;

  char* p = (char*)d_ws;
  auto take = [&](size_t bytes)->void*{ void* r = (void*)p; p += (bytes + 255) & ~(size_t)255; return r; };
  __hip_bfloat16* xb   = (__hip_bfloat16*)take((size_t)MTOT*D_*2);
  __hip_bfloat16* Wqt  = (__hip_bfloat16*)take((size_t)D_*D_*2);
  __hip_bfloat16* Wkt  = (__hip_bfloat16*)take((size_t)D_*D_*2);
  __hip_bfloat16* Wvt  = (__hip_bfloat16*)take((size_t)D_*D_*2);
  __hip_bfloat16* Wot  = (__hip_bfloat16*)take((size_t)D_*D_*2);
  __hip_bfloat16* Wg2t = (__hip_bfloat16*)take((size_t)D_*HD_*2);
  __hip_bfloat16* t1b  = (__hip_bfloat16*)take((size_t)MTOT*HD_*2);
  float* qf  = (float*)take((size_t)MTOT*D_*4);
  float* kf  = (float*)take((size_t)MTOT*D_*4);
  float* vf  = (float*)take((size_t)MTOT*D_*4);
  float* lrb = (float*)take((size_t)MTOT*H_*4);
  float* sob = (float*)take((size_t)MTOT*D_*4);
  __hip_bfloat16* yb = (__hip_bfloat16*)take((size_t)MTOT*D_*2);

  k_cast_bf16<<<MTOT*D_/4/256, 256, 0, stream>>>(x, xb, MTOT*D_/4);
  k_transpose_cast<<<dim3(16,16), 256, 0, stream>>>(Wq, Wqt, D_, D_);
  k_transpose_cast<<<dim3(16,16), 256, 0, stream>>>(Wk, Wkt, D_, D_);
  k_transpose_cast<<<dim3(16,16), 256, 0, stream>>>(Wv, Wvt, D_, D_);
  k_transpose_cast<<<dim3(16,16), 256, 0, stream>>>(Wo, Wot, D_, D_);
  k_transpose_cast<<<dim3(16,1),  256, 0, stream>>>(Wg2, Wg2t, HD_, D_);
  k_small_proj<<<MTOT, 256, 0, stream>>>(x, Wg1, Wlr, t1b, lrb);
  // q,k,v projections (silu on q,k), scattered to [b][h][t][e]
  k_gemm_bt<1,1><<<dim3(8,64), 256, 0, stream>>>(xb, Wqt, qf, MTOT, D_, D_);
  k_gemm_bt<1,1><<<dim3(8,64), 256, 0, stream>>>(xb, Wkt, kf, MTOT, D_, D_);
  k_gemm_bt<0,1><<<dim3(8,64), 256, 0, stream>>>(xb, Wvt, vf, MTOT, D_, D_);
  // gate pre-activation into d_out (free scratch until final GEMM)
  k_gemm_bt<0,0><<<dim3(8,64), 256, 0, stream>>>(t1b, Wg2t, out, MTOT, D_, HD_);
  k_scan3<<<256, 256, 0, stream>>>(qf, kf, vf, lrb, w1i, w3i, sob);
  k_norm_gate<<<MTOT*H_/4, 256, 0, stream>>>(sob, out, nw, yb);
  k_gemm_bt<0,0><<<dim3(8,64), 256, 0, stream>>>(yb, Wot, out, MTOT, D_, D_);
}

// Round 4
// 1197.099 us; speedup vs baseline: 2.6490x; 1.0328x over previous
//
#include <hip/hip_runtime.h>
#include <hip/hip_bf16.h>

#define B_ 4
#define N_ 2048
#define D_ 1024
#define H_ 16
#define HD_ 64
#define MTOT (B_*N_)   // 8192

typedef __attribute__((ext_vector_type(8))) short short8v;
typedef __attribute__((ext_vector_type(4))) float f32x4;

// ---------------- cast x -> bf16 (vectorized) ----------------
__global__ void k_cast_bf16(const float* __restrict__ in, __hip_bfloat16* __restrict__ out, int n4){
  int i = blockIdx.x*256 + threadIdx.x;
  if (i >= n4) return;
  float4 vv = ((const float4*)in)[i];
  __hip_bfloat16 b0 = __float2bfloat16(vv.x), b1 = __float2bfloat16(vv.y),
                 b2 = __float2bfloat16(vv.z), b3 = __float2bfloat16(vv.w);
  ushort4 o;
  o.x = *(const unsigned short*)&b0; o.y = *(const unsigned short*)&b1;
  o.z = *(const unsigned short*)&b2; o.w = *(const unsigned short*)&b3;
  ((ushort4*)out)[i] = o;
}

// ---------------- transpose + cast: out[c][r] = in[r][c] ----------------
__global__ void k_transpose_cast(const float* __restrict__ in, __hip_bfloat16* __restrict__ out,
                                 int R, int C){
  __shared__ float tile[64][65];
  int r0 = blockIdx.y*64, c0 = blockIdx.x*64;
  int tid = threadIdx.x;
  #pragma unroll
  for (int i=0;i<16;i++){ int idx = tid + i*256; int rr = idx>>6, cc = idx&63;
    tile[rr][cc] = in[(size_t)(r0+rr)*C + (c0+cc)]; }
  __syncthreads();
  #pragma unroll
  for (int i=0;i<16;i++){ int idx = tid + i*256; int rr = idx>>6, cc = idx&63;
    out[(size_t)(c0+rr)*R + (r0+cc)] = __float2bfloat16(tile[cc][rr]); }
}

// ---------------- small projections: t1 = x@Wg1 (bf16), lr = 0.01*sigmoid(x@Wlr) ----------------
__global__ __launch_bounds__(256) void k_small_proj(const float* __restrict__ x,
    const float* __restrict__ Wg1, const float* __restrict__ Wlr,
    __hip_bfloat16* __restrict__ t1, float* __restrict__ lrout)
{
  __shared__ float xs[1024];
  __shared__ float red[256];
  int m = blockIdx.x, tid = threadIdx.x;
  for (int i=tid;i<1024;i+=256) xs[i] = x[(size_t)m*1024 + i];
  __syncthreads();
  int j = tid & 63, pp = tid >> 6;
  float acc = 0.f;
  for (int kk = pp*256; kk < pp*256+256; ++kk) acc = fmaf(xs[kk], Wg1[(size_t)kk*64 + j], acc);
  red[tid] = acc; __syncthreads();
  if (tid < 64) t1[(size_t)m*64 + tid] =
      __float2bfloat16(red[tid] + red[tid+64] + red[tid+128] + red[tid+192]);
  __syncthreads();
  int hh = tid & 15, p2 = tid >> 4;
  float a2 = 0.f;
  for (int kk = p2*64; kk < p2*64+64; ++kk) a2 = fmaf(xs[kk], Wlr[(size_t)kk*16 + hh], a2);
  red[tid] = a2; __syncthreads();
  if (tid < 16){
    float s = 0.f;
    #pragma unroll
    for (int p3=0;p3<16;p3++) s += red[hh + p3*16];
    lrout[(size_t)m*16 + hh] = 0.01f/(1.0f + __expf(-s));
  }
}

// ---------------- bf16 MFMA GEMM: C = act(A @ BT^T), A:(M,K) BT:(N,K) bf16, C fp32 ----------------
// ACT: 0 none, 1 silu.  LAYOUT: 0 -> C[m*N+col]; 1 -> C[((b*16+h)*2048+t)*64+e] scatter (q/k/v)
template<int ACT, int LAYOUT>
__global__ __launch_bounds__(256,2) void k_gemm_bt(
    const __hip_bfloat16* __restrict__ A, const __hip_bfloat16* __restrict__ BT,
    float* __restrict__ C, int M, int N, int K)
{
  __shared__ short As[128][40];   // +8 pad: breaks 8-way bank conflict on b128 frag reads
  __shared__ short Bs[128][40];
  const int n0 = blockIdx.x*128, m0 = blockIdx.y*128;
  const int tid = threadIdx.x, lane = tid & 63, wid = tid >> 6;
  const int wm = wid >> 1, wn = wid & 1;
  const short* Aps = (const short*)A;
  const short* Bps = (const short*)BT;
  f32x4 acc[4][4] = {};
  const int r = tid >> 2, seg = (tid & 3)*8;
  for (int kk = 0; kk < K; kk += 32) {
    short8v a0 = *(const short8v*)(Aps + (size_t)(m0+r)*K + kk + seg);
    short8v a1 = *(const short8v*)(Aps + (size_t)(m0+r+64)*K + kk + seg);
    short8v b0 = *(const short8v*)(Bps + (size_t)(n0+r)*K + kk + seg);
    short8v b1 = *(const short8v*)(Bps + (size_t)(n0+r+64)*K + kk + seg);
    __syncthreads();
    *(short8v*)(&As[r][seg])    = a0;
    *(short8v*)(&As[r+64][seg]) = a1;
    *(short8v*)(&Bs[r][seg])    = b0;
    *(short8v*)(&Bs[r+64][seg]) = b1;
    __syncthreads();
    const int row = lane & 15, kq = (lane >> 4)*8;
    short8v af[4], bfr[4];
    #pragma unroll
    for (int i=0;i<4;i++) af[i]  = *(const short8v*)(&As[wm*64 + i*16 + row][kq]);
    #pragma unroll
    for (int j=0;j<4;j++) bfr[j] = *(const short8v*)(&Bs[wn*64 + j*16 + row][kq]);
    #pragma unroll
    for (int i=0;i<4;i++)
      #pragma unroll
      for (int j=0;j<4;j++)
        acc[i][j] = __builtin_amdgcn_mfma_f32_16x16x32_bf16(af[i], bfr[j], acc[i][j], 0, 0, 0);
  }
  #pragma unroll
  for (int i=0;i<4;i++){
    #pragma unroll
    for (int j=0;j<4;j++){
      int col = n0 + wn*64 + j*16 + (lane & 15);
      #pragma unroll
      for (int qq=0; qq<4; ++qq){
        int rowg = m0 + wm*64 + i*16 + (lane>>4)*4 + qq;
        float val = acc[i][j][qq];
        if (ACT==1) val = val/(1.0f+__expf(-val));
        if (LAYOUT==0) {
          C[(size_t)rowg*N + col] = val;
        } else {
          size_t oidx = ((((size_t)(rowg>>11))*16 + (col>>6))*(size_t)N_ + (size_t)(rowg & 2047))*64
                        + (size_t)(col & 63);
          C[oidx] = val;
        }
      }
    }
  }
}

// ---------------- DPP 16-lane reduction: rotate-and-add within DPP row ----------------
__device__ __forceinline__ float red16(float x){
  int r;
  r = __builtin_amdgcn_update_dpp(0, __float_as_int(x), 0x128, 0xF, 0xF, true); // row_ror:8
  x += __int_as_float(r);
  r = __builtin_amdgcn_update_dpp(0, __float_as_int(x), 0x124, 0xF, 0xF, true); // row_ror:4
  x += __int_as_float(r);
  r = __builtin_amdgcn_update_dpp(0, __float_as_int(x), 0x122, 0xF, 0xF, true); // row_ror:2
  x += __int_as_float(r);
  r = __builtin_amdgcn_update_dpp(0, __float_as_int(x), 0x121, 0xF, 0xF, true); // row_ror:1
  x += __int_as_float(r);
  return x;
}

__device__ __forceinline__ float dot4(const float4 a, const float4 b){
  return fmaf(a.x, b.x, fmaf(a.y, b.y, fmaf(a.z, b.z, a.w*b.w)));
}

// ---------------- fast-weight scan: algebraic deferral of the rank-1 update ----------------
// h(t+1) = k(t+1)·W^(t) - c(t)*(k(t+1)·k(t));  o(t) = q(t)·W^(t) - c(t)*(q(t)·k(t)).
// All six dot-reduces depend only on W^(t) and loaded tokens -> they run in parallel
// with the activation chain; per-step critical path = activation + 1 fma.
__global__ __launch_bounds__(256,1) void k_scan4(
    const float* __restrict__ q, const float* __restrict__ k, const float* __restrict__ v,
    const float* __restrict__ lr, const float* __restrict__ w1i, const float* __restrict__ w3i,
    float* __restrict__ so)
{
  const int blk = blockIdx.x;      // 0..255
  const int bh  = blk >> 2;        // b*16+h
  const int jb  = blk & 3;         // 16-column slab
  const int b = bh >> 4, h = bh & 15;
  const int tid = threadIdx.x;
  const int g = tid >> 4;          // column group (DPP-row aligned)
  const int l = tid & 15;          // lane in group; owns rows 4l..4l+3
  const int e = jb*16 + g;

  const float* w1p = w1i + (size_t)h*HD_*HD_ + e;
  const float* w3p = w3i + (size_t)h*HD_*HD_ + e;
  float4 w1, w3;
  w1.x = w1p[(4*l+0)*64]; w1.y = w1p[(4*l+1)*64]; w1.z = w1p[(4*l+2)*64]; w1.w = w1p[(4*l+3)*64];
  w3.x = w3p[(4*l+0)*64]; w3.y = w3p[(4*l+1)*64]; w3.z = w3p[(4*l+2)*64]; w3.w = w3p[(4*l+3)*64];

  const float* kb = k + (size_t)bh*N_*64 + 4*l;   // [b][h][t][d]
  const float* qb = q + (size_t)bh*N_*64 + 4*l;
  const float* vb = v + (size_t)bh*N_*64 + e;
  const float* lb = lr + (size_t)b*N_*16 + h;
  float* sop = so + ((size_t)b*N_*16 + h)*64 + e;  // [b][t][h][e]

  // prefetch t=0, t=1
  float4 k4  = *(const float4*)(kb);
  float4 q4  = *(const float4*)(qb);
  float  vv  = vb[0];
  float  lt  = lb[0];
  float4 k4n = *(const float4*)(kb + 64);
  float4 q4n = *(const float4*)(qb + 64);
  float  vvn = vb[64];
  float  ltn = lb[16];

  float h1 = red16(dot4(k4, w1));
  float h3 = red16(dot4(k4, w3));

  #pragma unroll 1
  for (int t = 0; t < N_; ++t) {
    // ---- pre-dots: depend only on W^(t) and tokens; off the activation chain ----
    const float KK  = red16(dot4(k4n, k4));
    const float QK  = red16(dot4(q4,  k4));
    const float H1n = red16(dot4(k4n, w1));
    const float H3n = red16(dot4(k4n, w3));
    const float Q1  = red16(dot4(q4,  w1));
    const float Q3  = red16(dot4(q4,  w3));

    // ---- activation / gradient for token t ----
    const float sg = 1.0f/(1.0f + __expf(-h1));
    const float s1 = h1*sg;                    // silu(h1)
    const float er = fmaf(s1, h3, -vv);
    const float ds = sg*fmaf(h1, 1.0f - sg, 1.0f);
    const float c1 = lt*(er*h3*ds);
    const float c3 = lt*(er*s1);

    // ---- outputs for t and h for t+1 via deferral (1 fma each) ----
    const float o1 = fmaf(-c1, QK, Q1);
    const float o3 = fmaf(-c3, QK, Q3);
    h1 = fmaf(-c1, KK, H1n);
    h3 = fmaf(-c3, KK, H3n);

    // ---- W update (off critical path; needed by next iteration's pre-dots) ----
    w1.x = fmaf(-k4.x, c1, w1.x); w1.y = fmaf(-k4.y, c1, w1.y);
    w1.z = fmaf(-k4.z, c1, w1.z); w1.w = fmaf(-k4.w, c1, w1.w);
    w3.x = fmaf(-k4.x, c3, w3.x); w3.y = fmaf(-k4.y, c3, w3.y);
    w3.z = fmaf(-k4.z, c3, w3.z); w3.w = fmaf(-k4.w, c3, w3.w);

    if (l == 0) {
      sop[(size_t)t*(H_*HD_)] = (o1/(1.0f + __expf(-o1)))*o3;
    }

    // ---- prefetch t+2 and shift ----
    const int tn = (t + 2 < N_) ? (t + 2) : (N_ - 1);
    const float4 k4p = *(const float4*)(kb + (size_t)tn*64);
    const float4 q4p = *(const float4*)(qb + (size_t)tn*64);
    const float  vvp = vb[(size_t)tn*64];
    const float  ltp = lb[(size_t)tn*16];
    k4 = k4n; q4 = q4n; vv = vvn; lt = ltn;
    k4n = k4p; q4n = q4p; vvn = vvp; ltn = ltp;
  }
}

// ---------------- grouped RMSNorm * norm_w * sigmoid(gate) -> bf16 y ----------------
__global__ void k_norm_gate(const float* __restrict__ so, const float* __restrict__ gate,
                            const float* __restrict__ nw, __hip_bfloat16* __restrict__ y)
{
  int idx = blockIdx.x*4 + (threadIdx.x>>6);  // (b*N+t)*16+h
  int e = threadIdx.x & 63;
  float o = so[(size_t)idx*64 + e];
  float ss = o*o;
  #pragma unroll
  for (int m=32; m>=1; m>>=1) ss += __shfl_xor(ss, m, 64);
  float rms = rsqrtf(ss*(1.0f/64.0f) + 1e-6f);
  int hh = idx & 15;
  size_t bn = (size_t)(idx >> 4);
  int d = hh*64 + e;
  float g = gate[bn*1024 + d];
  float val = o*rms*nw[d] * (1.0f/(1.0f+__expf(-g)));
  y[bn*1024 + d] = __float2bfloat16(val);
}

extern "C" void kernel_launch(void* const* d_in, const int* in_sizes, int n_in,
                              void* d_out, int out_size, void* d_ws, size_t ws_size,
                              hipStream_t stream)
{
  const float* x   = (const float*)d_in[0];
  const float* Wq  = (const float*)d_in[1];
  const float* Wk  = (const float*)d_in[2];
  const float* Wv  = (const float*)d_in[3];
  const float* Wo  = (const float*)d_in[4];
  const float* w1i = (const float*)d_in[5];
  const float* w3i = (const float*)d_in[6];
  const float* Wlr = (const float*)d_in[7];
  const float* nw  = (const float*)d_in[8];
  const float* Wg1 = (const float*)d_in[9];
  const float* Wg2 = (const float*)d_in[10];
  float* out = (float*)d_out;

  char* p = (char*)d_ws;
  auto take = [&](size_t bytes)->void*{ void* r = (void*)p; p += (bytes + 255) & ~(size_t)255; return r; };
  __hip_bfloat16* xb   = (__hip_bfloat16*)take((size_t)MTOT*D_*2);
  __hip_bfloat16* Wqt  = (__hip_bfloat16*)take((size_t)D_*D_*2);
  __hip_bfloat16* Wkt  = (__hip_bfloat16*)take((size_t)D_*D_*2);
  __hip_bfloat16* Wvt  = (__hip_bfloat16*)take((size_t)D_*D_*2);
  __hip_bfloat16* Wot  = (__hip_bfloat16*)take((size_t)D_*D_*2);
  __hip_bfloat16* Wg2t = (__hip_bfloat16*)take((size_t)D_*HD_*2);
  __hip_bfloat16* t1b  = (__hip_bfloat16*)take((size_t)MTOT*HD_*2);
  float* qf  = (float*)take((size_t)MTOT*D_*4);
  float* kf  = (float*)take((size_t)MTOT*D_*4);
  float* vf  = (float*)take((size_t)MTOT*D_*4);
  float* lrb = (float*)take((size_t)MTOT*H_*4);
  float* sob = (float*)take((size_t)MTOT*D_*4);
  __hip_bfloat16* yb = (__hip_bfloat16*)take((size_t)MTOT*D_*2);

  k_cast_bf16<<<MTOT*D_/4/256, 256, 0, stream>>>(x, xb, MTOT*D_/4);
  k_transpose_cast<<<dim3(16,16), 256, 0, stream>>>(Wq, Wqt, D_, D_);
  k_transpose_cast<<<dim3(16,16), 256, 0, stream>>>(Wk, Wkt, D_, D_);
  k_transpose_cast<<<dim3(16,16), 256, 0, stream>>>(Wv, Wvt, D_, D_);
  k_transpose_cast<<<dim3(16,16), 256, 0, stream>>>(Wo, Wot, D_, D_);
  k_transpose_cast<<<dim3(16,1),  256, 0, stream>>>(Wg2, Wg2t, HD_, D_);
  k_small_proj<<<MTOT, 256, 0, stream>>>(x, Wg1, Wlr, t1b, lrb);
  // q,k,v projections (silu on q,k), scattered to [b][h][t][e]
  k_gemm_bt<1,1><<<dim3(8,64), 256, 0, stream>>>(xb, Wqt, qf, MTOT, D_, D_);
  k_gemm_bt<1,1><<<dim3(8,64), 256, 0, stream>>>(xb, Wkt, kf, MTOT, D_, D_);
  k_gemm_bt<0,1><<<dim3(8,64), 256, 0, stream>>>(xb, Wvt, vf, MTOT, D_, D_);
  // gate pre-activation into d_out (free scratch until final GEMM)
  k_gemm_bt<0,0><<<dim3(8,64), 256, 0, stream>>>(t1b, Wg2t, out, MTOT, D_, HD_);
  k_scan4<<<256, 256, 0, stream>>>(qf, kf, vf, lrb, w1i, w3i, sob);
  k_norm_gate<<<MTOT*H_/4, 256, 0, stream>>>(sob, out, nw, yb);
  k_gemm_bt<0,0><<<dim3(8,64), 256, 0, stream>>>(yb, Wot, out, MTOT, D_, D_);
}

// Round 5
// 989.270 us; speedup vs baseline: 3.2055x; 1.2101x over previous
//
#include <hip/hip_runtime.h>
#include <hip/hip_bf16.h>

#define B_ 4
#define N_ 2048
#define D_ 1024
#define H_ 16
#define HD_ 64
#define MTOT (B_*N_)   // 8192
#define CH_ 16         // scan chunk size
#define NCH_ (N_/CH_)  // 128

typedef __attribute__((ext_vector_type(8))) short short8v;
typedef __attribute__((ext_vector_type(4))) float f32x4;

// ---------------- cast x -> bf16 (vectorized) ----------------
__global__ void k_cast_bf16(const float* __restrict__ in, __hip_bfloat16* __restrict__ out, int n4){
  int i = blockIdx.x*256 + threadIdx.x;
  if (i >= n4) return;
  float4 vv = ((const float4*)in)[i];
  __hip_bfloat16 b0 = __float2bfloat16(vv.x), b1 = __float2bfloat16(vv.y),
                 b2 = __float2bfloat16(vv.z), b3 = __float2bfloat16(vv.w);
  ushort4 o;
  o.x = *(const unsigned short*)&b0; o.y = *(const unsigned short*)&b1;
  o.z = *(const unsigned short*)&b2; o.w = *(const unsigned short*)&b3;
  ((ushort4*)out)[i] = o;
}

// ---------------- transpose + cast: out[c][r] = in[r][c] ----------------
__global__ void k_transpose_cast(const float* __restrict__ in, __hip_bfloat16* __restrict__ out,
                                 int R, int C){
  __shared__ float tile[64][65];
  int r0 = blockIdx.y*64, c0 = blockIdx.x*64;
  int tid = threadIdx.x;
  #pragma unroll
  for (int i=0;i<16;i++){ int idx = tid + i*256; int rr = idx>>6, cc = idx&63;
    tile[rr][cc] = in[(size_t)(r0+rr)*C + (c0+cc)]; }
  __syncthreads();
  #pragma unroll
  for (int i=0;i<16;i++){ int idx = tid + i*256; int rr = idx>>6, cc = idx&63;
    out[(size_t)(c0+rr)*R + (r0+cc)] = __float2bfloat16(tile[cc][rr]); }
}

// ---------------- small projections: t1 = x@Wg1 (bf16), lr = 0.01*sigmoid(x@Wlr) ----------------
__global__ __launch_bounds__(256) void k_small_proj(const float* __restrict__ x,
    const float* __restrict__ Wg1, const float* __restrict__ Wlr,
    __hip_bfloat16* __restrict__ t1, float* __restrict__ lrout)
{
  __shared__ float xs[1024];
  __shared__ float red[256];
  int m = blockIdx.x, tid = threadIdx.x;
  for (int i=tid;i<1024;i+=256) xs[i] = x[(size_t)m*1024 + i];
  __syncthreads();
  int j = tid & 63, pp = tid >> 6;
  float acc = 0.f;
  for (int kk = pp*256; kk < pp*256+256; ++kk) acc = fmaf(xs[kk], Wg1[(size_t)kk*64 + j], acc);
  red[tid] = acc; __syncthreads();
  if (tid < 64) t1[(size_t)m*64 + tid] =
      __float2bfloat16(red[tid] + red[tid+64] + red[tid+128] + red[tid+192]);
  __syncthreads();
  int hh = tid & 15, p2 = tid >> 4;
  float a2 = 0.f;
  for (int kk = p2*64; kk < p2*64+64; ++kk) a2 = fmaf(xs[kk], Wlr[(size_t)kk*16 + hh], a2);
  red[tid] = a2; __syncthreads();
  if (tid < 16){
    float s = 0.f;
    #pragma unroll
    for (int p3=0;p3<16;p3++) s += red[hh + p3*16];
    lrout[(size_t)m*16 + hh] = 0.01f/(1.0f + __expf(-s));
  }
}

// ---------------- bf16 MFMA GEMM: C = act(A @ BT^T), A:(M,K) BT:(N,K) bf16, C fp32 ----------------
template<int ACT, int LAYOUT>
__global__ __launch_bounds__(256,2) void k_gemm_bt(
    const __hip_bfloat16* __restrict__ A, const __hip_bfloat16* __restrict__ BT,
    float* __restrict__ C, int M, int N, int K)
{
  __shared__ short As[128][40];
  __shared__ short Bs[128][40];
  const int n0 = blockIdx.x*128, m0 = blockIdx.y*128;
  const int tid = threadIdx.x, lane = tid & 63, wid = tid >> 6;
  const int wm = wid >> 1, wn = wid & 1;
  const short* Aps = (const short*)A;
  const short* Bps = (const short*)BT;
  f32x4 acc[4][4] = {};
  const int r = tid >> 2, seg = (tid & 3)*8;
  for (int kk = 0; kk < K; kk += 32) {
    short8v a0 = *(const short8v*)(Aps + (size_t)(m0+r)*K + kk + seg);
    short8v a1 = *(const short8v*)(Aps + (size_t)(m0+r+64)*K + kk + seg);
    short8v b0 = *(const short8v*)(Bps + (size_t)(n0+r)*K + kk + seg);
    short8v b1 = *(const short8v*)(Bps + (size_t)(n0+r+64)*K + kk + seg);
    __syncthreads();
    *(short8v*)(&As[r][seg])    = a0;
    *(short8v*)(&As[r+64][seg]) = a1;
    *(short8v*)(&Bs[r][seg])    = b0;
    *(short8v*)(&Bs[r+64][seg]) = b1;
    __syncthreads();
    const int row = lane & 15, kq = (lane >> 4)*8;
    short8v af[4], bfr[4];
    #pragma unroll
    for (int i=0;i<4;i++) af[i]  = *(const short8v*)(&As[wm*64 + i*16 + row][kq]);
    #pragma unroll
    for (int j=0;j<4;j++) bfr[j] = *(const short8v*)(&Bs[wn*64 + j*16 + row][kq]);
    #pragma unroll
    for (int i=0;i<4;i++)
      #pragma unroll
      for (int j=0;j<4;j++)
        acc[i][j] = __builtin_amdgcn_mfma_f32_16x16x32_bf16(af[i], bfr[j], acc[i][j], 0, 0, 0);
  }
  #pragma unroll
  for (int i=0;i<4;i++){
    #pragma unroll
    for (int j=0;j<4;j++){
      int col = n0 + wn*64 + j*16 + (lane & 15);
      #pragma unroll
      for (int qq=0; qq<4; ++qq){
        int rowg = m0 + wm*64 + i*16 + (lane>>4)*4 + qq;
        float val = acc[i][j][qq];
        if (ACT==1) val = val/(1.0f+__expf(-val));
        if (LAYOUT==0) {
          C[(size_t)rowg*N + col] = val;
        } else {
          size_t oidx = ((((size_t)(rowg>>11))*16 + (col>>6))*(size_t)N_ + (size_t)(rowg & 2047))*64
                        + (size_t)(col & 63);
          C[oidx] = val;
        }
      }
    }
  }
}

// ---------------- helpers for chunked scan ----------------
__device__ __forceinline__ unsigned short bfr16(float x){
  __hip_bfloat16 b = __float2bfloat16(x);
  return *(unsigned short*)&b;
}
// load 8 contiguous fp32, convert to a bf16 MFMA fragment
__device__ __forceinline__ short8v ld_frag(const float* p){
  float4 a = *(const float4*)p;
  float4 c = *(const float4*)(p+4);
  short8v r;
  r[0]=(short)bfr16(a.x); r[1]=(short)bfr16(a.y); r[2]=(short)bfr16(a.z); r[3]=(short)bfr16(a.w);
  r[4]=(short)bfr16(c.x); r[5]=(short)bfr16(c.y); r[6]=(short)bfr16(c.z); r[7]=(short)bfr16(c.w);
  return r;
}

// ---------------- chunked fast-weight scan ----------------
// 256 blocks = 64 (b,h) x 4 e-slabs(16 cols). Block=256 thr (4 waves).
// Per chunk (C=16): A: MFMA products KW1,KW3,QW1,QW3 (K_c@W, Q_c@W vs bf16 LDS
// mirror of W) + Gram KK,QK; B: wave0 serial 16 tokens (lane=e, corrections
// from register c-history + broadcast Gram); C: rank-16 W update (W master in
// 8 VGPR/thread) + rewrite bf16 mirror.
__global__ __launch_bounds__(256,1) void k_scan5(
    const float* __restrict__ q, const float* __restrict__ k, const float* __restrict__ v,
    const float* __restrict__ lr, const float* __restrict__ w1i, const float* __restrict__ w3i,
    float* __restrict__ so)
{
  const int blk = blockIdx.x;            // 0..255
  const int bh  = blk >> 2;              // b*16+h
  const int sl  = blk & 3;               // e-slab
  const int b = bh >> 4, h = bh & 15;
  const int e0 = sl*16;
  const int tid = threadIdx.x, lane = tid & 63, wid = tid >> 6;

  __shared__ __align__(16) __hip_bfloat16 Wb1[16*64];   // mirror [e][d], XOR-swizzled
  __shared__ __align__(16) __hip_bfloat16 Wb3[16*64];
  __shared__ __align__(16) float KW1[256], KW3[256], QW1[256], QW3[256];  // [t][e]
  __shared__ __align__(16) float GKK[256], GQK[256];    // [t][s]
  __shared__ __align__(16) float VT[256];               // [t][e]
  __shared__ float LRT[16];
  __shared__ __align__(16) float C13[16*16*2];          // [s][e][{c1,c3}]

  // W master: thread owns (e = tid&15 within slab, rows wd..wd+3)
  const int we = tid & 15;
  const int wd = (tid >> 4) * 4;
  float w1r[4], w3r[4];
  {
    const float* w1p = w1i + (size_t)h*HD_*HD_ + e0 + we;
    const float* w3p = w3i + (size_t)h*HD_*HD_ + e0 + we;
    #pragma unroll
    for (int j=0;j<4;j++){ w1r[j] = w1p[(size_t)(wd+j)*64]; w3r[j] = w3p[(size_t)(wd+j)*64]; }
  }
  const int mir_off = we*128 + ((wd*2) ^ ((we&7)<<4));  // byte offset, 8B aligned
  auto write_mirrors = [&](){
    uint2 p1, p3;
    p1.x = (unsigned)bfr16(w1r[0]) | ((unsigned)bfr16(w1r[1])<<16);
    p1.y = (unsigned)bfr16(w1r[2]) | ((unsigned)bfr16(w1r[3])<<16);
    p3.x = (unsigned)bfr16(w3r[0]) | ((unsigned)bfr16(w3r[1])<<16);
    p3.y = (unsigned)bfr16(w3r[2]) | ((unsigned)bfr16(w3r[3])<<16);
    *(uint2*)((char*)Wb1 + mir_off) = p1;
    *(uint2*)((char*)Wb3 + mir_off) = p3;
  };
  write_mirrors();

  const float* kfb = k + (size_t)bh*N_*64;
  const float* qfb = q + (size_t)bh*N_*64;
  const float* vfb = v + (size_t)bh*N_*64;

  __syncthreads();

  #pragma unroll 1
  for (int c = 0; c < NCH_; ++c) {
    const int t0 = c*CH_;

    // ---- stage v, lr for this chunk ----
    VT[tid] = vfb[(size_t)(t0 + (tid>>4))*64 + e0 + (tid&15)];
    if (tid < 16) LRT[tid] = lr[((size_t)b*N_ + t0 + tid)*16 + h];

    // ---- phase A: MFMA products ----
    {
      const int tA  = lane & 15;
      const int ks8 = (lane >> 4) * 8;
      const float* krow = kfb + (size_t)(t0 + tA)*64;
      const float* qrow = qfb + (size_t)(t0 + tA)*64;
      auto xw = [&](const float* X, const __hip_bfloat16* Wm, float* dst){
        f32x4 acc = {};
        #pragma unroll
        for (int m=0;m<2;++m){
          short8v af = ld_frag(X + m*32 + ks8);
          short8v bf = *(const short8v*)((const char*)Wm + tA*128 + (((m*32+ks8)*2) ^ ((tA&7)<<4)));
          acc = __builtin_amdgcn_mfma_f32_16x16x32_bf16(af, bf, acc, 0, 0, 0);
        }
        #pragma unroll
        for (int qq=0;qq<4;++qq) dst[((lane>>4)*4+qq)*16 + tA] = acc[qq];
      };
      if (wid == 0)      xw(krow, Wb1, KW1);
      else if (wid == 1) xw(krow, Wb3, KW3);
      else if (wid == 2) {
        xw(qrow, Wb1, QW1);
        f32x4 acc = {};
        #pragma unroll
        for (int m=0;m<2;++m){
          short8v af = ld_frag(krow + m*32 + ks8);
          acc = __builtin_amdgcn_mfma_f32_16x16x32_bf16(af, af, acc, 0, 0, 0);
        }
        #pragma unroll
        for (int qq=0;qq<4;++qq) GKK[((lane>>4)*4+qq)*16 + tA] = acc[qq];
      } else {
        xw(qrow, Wb3, QW3);
        f32x4 acc = {};
        #pragma unroll
        for (int m=0;m<2;++m){
          short8v af = ld_frag(qrow + m*32 + ks8);
          short8v bf = ld_frag(krow + m*32 + ks8);
          acc = __builtin_amdgcn_mfma_f32_16x16x32_bf16(af, bf, acc, 0, 0, 0);
        }
        #pragma unroll
        for (int qq=0;qq<4;++qq) GQK[((lane>>4)*4+qq)*16 + tA] = acc[qq];
      }
    }
    __syncthreads();

    // ---- phase B: serial tokens (wave0, 16 lanes) ----
    if (wid == 0 && lane < 16) {
      float2 c13[CH_];
      float* sop = so + (((size_t)b*N_ + t0)*16 + h)*64 + e0 + lane;
      #pragma unroll
      for (int t = 0; t < CH_; ++t) {
        // gram rows -> static regs
        float gk[16], gq[16];
        #pragma unroll
        for (int si=0; si<4; ++si){
          if (si*4 < t){
            float4 a = *(const float4*)&GKK[t*16+si*4];
            gk[si*4]=a.x; gk[si*4+1]=a.y; gk[si*4+2]=a.z; gk[si*4+3]=a.w;
          }
          if (si*4 <= t){
            float4 a = *(const float4*)&GQK[t*16+si*4];
            gq[si*4]=a.x; gq[si*4+1]=a.y; gq[si*4+2]=a.z; gq[si*4+3]=a.w;
          }
        }
        float h1 = KW1[t*16+lane], h3 = KW3[t*16+lane];
        #pragma unroll
        for (int s = 0; s < t; ++s) {
          h1 = fmaf(-gk[s], c13[s].x, h1);
          h3 = fmaf(-gk[s], c13[s].y, h3);
        }
        const float sg = 1.0f/(1.0f + __expf(-h1));
        const float s1 = h1*sg;
        const float er = fmaf(s1, h3, -VT[t*16+lane]);
        const float ds = sg*fmaf(h1, 1.0f - sg, 1.0f);
        const float lt = LRT[t];
        float2 cc; cc.x = lt*(er*h3*ds); cc.y = lt*(er*s1);
        c13[t] = cc;
        *(float2*)&C13[(t*16+lane)*2] = cc;
        float o1 = QW1[t*16+lane], o3 = QW3[t*16+lane];
        #pragma unroll
        for (int s = 0; s <= t; ++s) {
          o1 = fmaf(-gq[s], c13[s].x, o1);
          o3 = fmaf(-gq[s], c13[s].y, o3);
        }
        sop[(size_t)t*(H_*HD_)] = (o1/(1.0f + __expf(-o1)))*o3;
      }
    }
    __syncthreads();

    // ---- phase C: rank-16 W update + rewrite mirror ----
    #pragma unroll
    for (int s = 0; s < CH_; ++s) {
      const float2 cc = *(const float2*)&C13[(s*16+we)*2];
      const float4 ks = *(const float4*)(kfb + (size_t)(t0+s)*64 + wd);
      w1r[0] = fmaf(-ks.x, cc.x, w1r[0]); w1r[1] = fmaf(-ks.y, cc.x, w1r[1]);
      w1r[2] = fmaf(-ks.z, cc.x, w1r[2]); w1r[3] = fmaf(-ks.w, cc.x, w1r[3]);
      w3r[0] = fmaf(-ks.x, cc.y, w3r[0]); w3r[1] = fmaf(-ks.y, cc.y, w3r[1]);
      w3r[2] = fmaf(-ks.z, cc.y, w3r[2]); w3r[3] = fmaf(-ks.w, cc.y, w3r[3]);
    }
    write_mirrors();
    __syncthreads();
  }
}

// ---------------- grouped RMSNorm * norm_w * sigmoid(gate) -> bf16 y ----------------
__global__ void k_norm_gate(const float* __restrict__ so, const float* __restrict__ gate,
                            const float* __restrict__ nw, __hip_bfloat16* __restrict__ y)
{
  int idx = blockIdx.x*4 + (threadIdx.x>>6);  // (b*N+t)*16+h
  int e = threadIdx.x & 63;
  float o = so[(size_t)idx*64 + e];
  float ss = o*o;
  #pragma unroll
  for (int m=32; m>=1; m>>=1) ss += __shfl_xor(ss, m, 64);
  float rms = rsqrtf(ss*(1.0f/64.0f) + 1e-6f);
  int hh = idx & 15;
  size_t bn = (size_t)(idx >> 4);
  int d = hh*64 + e;
  float g = gate[bn*1024 + d];
  float val = o*rms*nw[d] * (1.0f/(1.0f+__expf(-g)));
  y[bn*1024 + d] = __float2bfloat16(val);
}

extern "C" void kernel_launch(void* const* d_in, const int* in_sizes, int n_in,
                              void* d_out, int out_size, void* d_ws, size_t ws_size,
                              hipStream_t stream)
{
  const float* x   = (const float*)d_in[0];
  const float* Wq  = (const float*)d_in[1];
  const float* Wk  = (const float*)d_in[2];
  const float* Wv  = (const float*)d_in[3];
  const float* Wo  = (const float*)d_in[4];
  const float* w1i = (const float*)d_in[5];
  const float* w3i = (const float*)d_in[6];
  const float* Wlr = (const float*)d_in[7];
  const float* nw  = (const float*)d_in[8];
  const float* Wg1 = (const float*)d_in[9];
  const float* Wg2 = (const float*)d_in[10];
  float* out = (float*)d_out;

  char* p = (char*)d_ws;
  auto take = [&](size_t bytes)->void*{ void* r = (void*)p; p += (bytes + 255) & ~(size_t)255; return r; };
  __hip_bfloat16* xb   = (__hip_bfloat16*)take((size_t)MTOT*D_*2);
  __hip_bfloat16* Wqt  = (__hip_bfloat16*)take((size_t)D_*D_*2);
  __hip_bfloat16* Wkt  = (__hip_bfloat16*)take((size_t)D_*D_*2);
  __hip_bfloat16* Wvt  = (__hip_bfloat16*)take((size_t)D_*D_*2);
  __hip_bfloat16* Wot  = (__hip_bfloat16*)take((size_t)D_*D_*2);
  __hip_bfloat16* Wg2t = (__hip_bfloat16*)take((size_t)D_*HD_*2);
  __hip_bfloat16* t1b  = (__hip_bfloat16*)take((size_t)MTOT*HD_*2);
  float* qf  = (float*)take((size_t)MTOT*D_*4);
  float* kf  = (float*)take((size_t)MTOT*D_*4);
  float* vf  = (float*)take((size_t)MTOT*D_*4);
  float* lrb = (float*)take((size_t)MTOT*H_*4);
  float* sob = (float*)take((size_t)MTOT*D_*4);
  __hip_bfloat16* yb = (__hip_bfloat16*)take((size_t)MTOT*D_*2);

  k_cast_bf16<<<MTOT*D_/4/256, 256, 0, stream>>>(x, xb, MTOT*D_/4);
  k_transpose_cast<<<dim3(16,16), 256, 0, stream>>>(Wq, Wqt, D_, D_);
  k_transpose_cast<<<dim3(16,16), 256, 0, stream>>>(Wk, Wkt, D_, D_);
  k_transpose_cast<<<dim3(16,16), 256, 0, stream>>>(Wv, Wvt, D_, D_);
  k_transpose_cast<<<dim3(16,16), 256, 0, stream>>>(Wo, Wot, D_, D_);
  k_transpose_cast<<<dim3(16,1),  256, 0, stream>>>(Wg2, Wg2t, HD_, D_);
  k_small_proj<<<MTOT, 256, 0, stream>>>(x, Wg1, Wlr, t1b, lrb);
  // q,k,v projections (silu on q,k), scattered to [b][h][t][e]
  k_gemm_bt<1,1><<<dim3(8,64), 256, 0, stream>>>(xb, Wqt, qf, MTOT, D_, D_);
  k_gemm_bt<1,1><<<dim3(8,64), 256, 0, stream>>>(xb, Wkt, kf, MTOT, D_, D_);
  k_gemm_bt<0,1><<<dim3(8,64), 256, 0, stream>>>(xb, Wvt, vf, MTOT, D_, D_);
  // gate pre-activation into d_out (free scratch until final GEMM)
  k_gemm_bt<0,0><<<dim3(8,64), 256, 0, stream>>>(t1b, Wg2t, out, MTOT, D_, HD_);
  k_scan5<<<256, 256, 0, stream>>>(qf, kf, vf, lrb, w1i, w3i, sob);
  k_norm_gate<<<MTOT*H_/4, 256, 0, stream>>>(sob, out, nw, yb);
  k_gemm_bt<0,0><<<dim3(8,64), 256, 0, stream>>>(yb, Wot, out, MTOT, D_, D_);
}

// Round 6
// 924.498 us; speedup vs baseline: 3.4301x; 1.0701x over previous
//
#include <hip/hip_runtime.h>
#include <hip/hip_bf16.h>

#define B_ 4
#define N_ 2048
#define D_ 1024
#define H_ 16
#define HD_ 64
#define MTOT (B_*N_)   // 8192
#define CH_ 16         // scan chunk size
#define NCH_ (N_/CH_)  // 128

typedef __attribute__((ext_vector_type(8))) short short8v;
typedef __attribute__((ext_vector_type(4))) float f32x4;

// ---------------- cast x -> bf16 (vectorized) ----------------
__global__ void k_cast_bf16(const float* __restrict__ in, __hip_bfloat16* __restrict__ out, int n4){
  int i = blockIdx.x*256 + threadIdx.x;
  if (i >= n4) return;
  float4 vv = ((const float4*)in)[i];
  __hip_bfloat16 b0 = __float2bfloat16(vv.x), b1 = __float2bfloat16(vv.y),
                 b2 = __float2bfloat16(vv.z), b3 = __float2bfloat16(vv.w);
  ushort4 o;
  o.x = *(const unsigned short*)&b0; o.y = *(const unsigned short*)&b1;
  o.z = *(const unsigned short*)&b2; o.w = *(const unsigned short*)&b3;
  ((ushort4*)out)[i] = o;
}

// ---------------- transpose + cast: out[c][r] = in[r][c] ----------------
__global__ void k_transpose_cast(const float* __restrict__ in, __hip_bfloat16* __restrict__ out,
                                 int R, int C){
  __shared__ float tile[64][65];
  int r0 = blockIdx.y*64, c0 = blockIdx.x*64;
  int tid = threadIdx.x;
  #pragma unroll
  for (int i=0;i<16;i++){ int idx = tid + i*256; int rr = idx>>6, cc = idx&63;
    tile[rr][cc] = in[(size_t)(r0+rr)*C + (c0+cc)]; }
  __syncthreads();
  #pragma unroll
  for (int i=0;i<16;i++){ int idx = tid + i*256; int rr = idx>>6, cc = idx&63;
    out[(size_t)(c0+rr)*R + (r0+cc)] = __float2bfloat16(tile[cc][rr]); }
}

// ---------------- small projections: t1 = x@Wg1 (bf16), lr = 0.01*sigmoid(x@Wlr) ----------------
__global__ __launch_bounds__(256) void k_small_proj(const float* __restrict__ x,
    const float* __restrict__ Wg1, const float* __restrict__ Wlr,
    __hip_bfloat16* __restrict__ t1, float* __restrict__ lrout)
{
  __shared__ float xs[1024];
  __shared__ float red[256];
  int m = blockIdx.x, tid = threadIdx.x;
  for (int i=tid;i<1024;i+=256) xs[i] = x[(size_t)m*1024 + i];
  __syncthreads();
  int j = tid & 63, pp = tid >> 6;
  float acc = 0.f;
  for (int kk = pp*256; kk < pp*256+256; ++kk) acc = fmaf(xs[kk], Wg1[(size_t)kk*64 + j], acc);
  red[tid] = acc; __syncthreads();
  if (tid < 64) t1[(size_t)m*64 + tid] =
      __float2bfloat16(red[tid] + red[tid+64] + red[tid+128] + red[tid+192]);
  __syncthreads();
  int hh = tid & 15, p2 = tid >> 4;
  float a2 = 0.f;
  for (int kk = p2*64; kk < p2*64+64; ++kk) a2 = fmaf(xs[kk], Wlr[(size_t)kk*16 + hh], a2);
  red[tid] = a2; __syncthreads();
  if (tid < 16){
    float s = 0.f;
    #pragma unroll
    for (int p3=0;p3<16;p3++) s += red[hh + p3*16];
    lrout[(size_t)m*16 + hh] = 0.01f/(1.0f + __expf(-s));
  }
}

// ---------------- bf16 MFMA GEMM: C = act(A @ BT^T), A:(M,K) BT:(N,K) bf16, C fp32 ----------------
template<int ACT, int LAYOUT>
__global__ __launch_bounds__(256,2) void k_gemm_bt(
    const __hip_bfloat16* __restrict__ A, const __hip_bfloat16* __restrict__ BT,
    float* __restrict__ C, int M, int N, int K)
{
  __shared__ short As[128][40];
  __shared__ short Bs[128][40];
  const int n0 = blockIdx.x*128, m0 = blockIdx.y*128;
  const int tid = threadIdx.x, lane = tid & 63, wid = tid >> 6;
  const int wm = wid >> 1, wn = wid & 1;
  const short* Aps = (const short*)A;
  const short* Bps = (const short*)BT;
  f32x4 acc[4][4] = {};
  const int r = tid >> 2, seg = (tid & 3)*8;
  for (int kk = 0; kk < K; kk += 32) {
    short8v a0 = *(const short8v*)(Aps + (size_t)(m0+r)*K + kk + seg);
    short8v a1 = *(const short8v*)(Aps + (size_t)(m0+r+64)*K + kk + seg);
    short8v b0 = *(const short8v*)(Bps + (size_t)(n0+r)*K + kk + seg);
    short8v b1 = *(const short8v*)(Bps + (size_t)(n0+r+64)*K + kk + seg);
    __syncthreads();
    *(short8v*)(&As[r][seg])    = a0;
    *(short8v*)(&As[r+64][seg]) = a1;
    *(short8v*)(&Bs[r][seg])    = b0;
    *(short8v*)(&Bs[r+64][seg]) = b1;
    __syncthreads();
    const int row = lane & 15, kq = (lane >> 4)*8;
    short8v af[4], bfr[4];
    #pragma unroll
    for (int i=0;i<4;i++) af[i]  = *(const short8v*)(&As[wm*64 + i*16 + row][kq]);
    #pragma unroll
    for (int j=0;j<4;j++) bfr[j] = *(const short8v*)(&Bs[wn*64 + j*16 + row][kq]);
    #pragma unroll
    for (int i=0;i<4;i++)
      #pragma unroll
      for (int j=0;j<4;j++)
        acc[i][j] = __builtin_amdgcn_mfma_f32_16x16x32_bf16(af[i], bfr[j], acc[i][j], 0, 0, 0);
  }
  #pragma unroll
  for (int i=0;i<4;i++){
    #pragma unroll
    for (int j=0;j<4;j++){
      int col = n0 + wn*64 + j*16 + (lane & 15);
      #pragma unroll
      for (int qq=0; qq<4; ++qq){
        int rowg = m0 + wm*64 + i*16 + (lane>>4)*4 + qq;
        float val = acc[i][j][qq];
        if (ACT==1) val = val/(1.0f+__expf(-val));
        if (LAYOUT==0) {
          C[(size_t)rowg*N + col] = val;
        } else {
          size_t oidx = ((((size_t)(rowg>>11))*16 + (col>>6))*(size_t)N_ + (size_t)(rowg & 2047))*64
                        + (size_t)(col & 63);
          C[oidx] = val;
        }
      }
    }
  }
}

// ---------------- helpers for chunked scan ----------------
__device__ __forceinline__ unsigned short bfr16(float x){
  __hip_bfloat16 b = __float2bfloat16(x);
  return *(unsigned short*)&b;
}
// convert two float4 (8 contiguous fp32) into a bf16 MFMA fragment
__device__ __forceinline__ short8v cvt_frag(const float4 a, const float4 c){
  short8v r;
  r[0]=(short)bfr16(a.x); r[1]=(short)bfr16(a.y); r[2]=(short)bfr16(a.z); r[3]=(short)bfr16(a.w);
  r[4]=(short)bfr16(c.x); r[5]=(short)bfr16(c.y); r[6]=(short)bfr16(c.z); r[7]=(short)bfr16(c.w);
  return r;
}

// ---------------- chunked fast-weight scan, latency-hidden schedule ----------------
// 256 blocks = 64 (b,h) x 4 e-slabs(16 cols). Block=256 thr (4 waves).
// Per chunk: A: waves1-3 MFMA products (from regs prefetched last chunk) -> LDS;
// B: wave0 serial 16 tokens; waves1-3 issue c+1 prefetch loads then park at bar;
// C: all threads rank-16 master update (k rows L1-hot) + rewrite bf16 mirror.
__global__ __launch_bounds__(256,1) void k_scan6(
    const float* __restrict__ q, const float* __restrict__ k, const float* __restrict__ v,
    const float* __restrict__ lr, const float* __restrict__ w1i, const float* __restrict__ w3i,
    float* __restrict__ so)
{
  const int blk = blockIdx.x;            // 0..255
  const int bh  = blk >> 2;              // b*16+h
  const int sl  = blk & 3;               // e-slab
  const int b = bh >> 4, h = bh & 15;
  const int e0 = sl*16;
  const int tid = threadIdx.x, lane = tid & 63, wid = tid >> 6;
  const int tA = lane & 15, ks8 = (lane >> 4)*8;

  __shared__ __align__(16) __hip_bfloat16 Wb1[16*64];   // mirror [e][d], XOR-swizzled
  __shared__ __align__(16) __hip_bfloat16 Wb3[16*64];
  __shared__ __align__(16) float KW1[256], KW3[256], QW1[256], QW3[256];  // [t][e]
  __shared__ __align__(16) float GKK[256], GQK[256];    // [t][s]
  __shared__ __align__(16) float C13[16*16*2];          // [s][e][{c1,c3}]

  // W master: thread owns (e = tid&15 within slab, rows wd..wd+3)
  const int we = tid & 15;
  const int wd = (tid >> 4) * 4;
  float w1r[4], w3r[4];
  {
    const float* w1p = w1i + (size_t)h*HD_*HD_ + e0 + we;
    const float* w3p = w3i + (size_t)h*HD_*HD_ + e0 + we;
    #pragma unroll
    for (int j=0;j<4;j++){ w1r[j] = w1p[(size_t)(wd+j)*64]; w3r[j] = w3p[(size_t)(wd+j)*64]; }
  }
  const int mir_off = we*128 + ((wd*2) ^ ((we&7)<<4));  // byte offset, 8B aligned
  auto write_mirrors = [&](){
    uint2 p1, p3;
    p1.x = (unsigned)bfr16(w1r[0]) | ((unsigned)bfr16(w1r[1])<<16);
    p1.y = (unsigned)bfr16(w1r[2]) | ((unsigned)bfr16(w1r[3])<<16);
    p3.x = (unsigned)bfr16(w3r[0]) | ((unsigned)bfr16(w3r[1])<<16);
    p3.y = (unsigned)bfr16(w3r[2]) | ((unsigned)bfr16(w3r[3])<<16);
    *(uint2*)((char*)Wb1 + mir_off) = p1;
    *(uint2*)((char*)Wb3 + mir_off) = p3;
  };
  write_mirrors();

  const float* kfb = k + (size_t)bh*N_*64;
  const float* qfb = q + (size_t)bh*N_*64;
  const float* vfb = v + (size_t)bh*N_*64;
  const float* lrp = lr + ((size_t)b*N_)*16 + h;
  float* sob = so + (((size_t)b*N_)*16 + h)*64 + e0;

  // mirror read helper (B-operand frag for e=tA, k-slice m)
  auto mir_read = [&](const __hip_bfloat16* Wm, int m)->short8v{
    return *(const short8v*)((const char*)Wm + tA*128 + (((m*32+ks8)*2) ^ ((tA&7)<<4)));
  };

  // ---- prefetch registers (live across chunk iterations) ----
  float4 fA0,fA1,fA2,fA3;          // wave1: k frags; wave2: q frags; wave3: k frags
  float4 fB0,fB1,fB2,fB3;          // wave3: q frags
  float  vvr[16], lrr[16];         // wave0 lanes<16: v[t][e=lane], lr[t]

  // prologue: prefetch chunk 0
  if (wid >= 1) {
    const float* xr = ((wid==2) ? qfb : kfb) + (size_t)tA*64;
    fA0 = *(const float4*)(xr+ks8);    fA1 = *(const float4*)(xr+ks8+4);
    fA2 = *(const float4*)(xr+32+ks8); fA3 = *(const float4*)(xr+32+ks8+4);
    if (wid==3){
      const float* qr = qfb + (size_t)tA*64;
      fB0 = *(const float4*)(qr+ks8);    fB1 = *(const float4*)(qr+ks8+4);
      fB2 = *(const float4*)(qr+32+ks8); fB3 = *(const float4*)(qr+32+ks8+4);
    }
  } else if (lane < 16) {
    #pragma unroll
    for (int t=0;t<CH_;++t){
      vvr[t] = vfb[(size_t)t*64 + e0 + lane];
      lrr[t] = lrp[(size_t)t*16];
    }
  }
  __syncthreads();

  #pragma unroll 1
  for (int c = 0; c < NCH_; ++c) {
    const int t0 = c*CH_;

    // ---- phase A: MFMA products from prefetched regs (waves 1-3) ----
    if (wid >= 1) {
      short8v af0 = cvt_frag(fA0,fA1), af1 = cvt_frag(fA2,fA3);
      if (wid <= 2) {
        float* d0 = (wid==1) ? KW1 : QW1;
        float* d1 = (wid==1) ? KW3 : QW3;
        f32x4 acc = {};
        acc = __builtin_amdgcn_mfma_f32_16x16x32_bf16(af0, mir_read(Wb1,0), acc, 0,0,0);
        acc = __builtin_amdgcn_mfma_f32_16x16x32_bf16(af1, mir_read(Wb1,1), acc, 0,0,0);
        #pragma unroll
        for (int qq=0;qq<4;++qq) d0[((lane>>4)*4+qq)*16 + tA] = acc[qq];
        f32x4 ac3 = {};
        ac3 = __builtin_amdgcn_mfma_f32_16x16x32_bf16(af0, mir_read(Wb3,0), ac3, 0,0,0);
        ac3 = __builtin_amdgcn_mfma_f32_16x16x32_bf16(af1, mir_read(Wb3,1), ac3, 0,0,0);
        #pragma unroll
        for (int qq=0;qq<4;++qq) d1[((lane>>4)*4+qq)*16 + tA] = ac3[qq];
      } else {
        short8v aq0 = cvt_frag(fB0,fB1), aq1 = cvt_frag(fB2,fB3);
        f32x4 acc = {};
        acc = __builtin_amdgcn_mfma_f32_16x16x32_bf16(af0, af0, acc, 0,0,0);
        acc = __builtin_amdgcn_mfma_f32_16x16x32_bf16(af1, af1, acc, 0,0,0);
        #pragma unroll
        for (int qq=0;qq<4;++qq) GKK[((lane>>4)*4+qq)*16 + tA] = acc[qq];
        f32x4 ac2 = {};
        ac2 = __builtin_amdgcn_mfma_f32_16x16x32_bf16(aq0, af0, ac2, 0,0,0);
        ac2 = __builtin_amdgcn_mfma_f32_16x16x32_bf16(aq1, af1, ac2, 0,0,0);
        #pragma unroll
        for (int qq=0;qq<4;++qq) GQK[((lane>>4)*4+qq)*16 + tA] = ac2[qq];
      }
    }
    __syncthreads();   // bar1: A results visible

    // ---- phase B window ----
    const int tn0 = ((c+1 < NCH_) ? c+1 : c) * CH_;
    if (wid >= 1) {
      // issue chunk c+1 prefetch; park at bar2 while they fly under wave0's B
      const float* xr = ((wid==2) ? qfb : kfb) + (size_t)(tn0+tA)*64;
      fA0 = *(const float4*)(xr+ks8);    fA1 = *(const float4*)(xr+ks8+4);
      fA2 = *(const float4*)(xr+32+ks8); fA3 = *(const float4*)(xr+32+ks8+4);
      if (wid==3){
        const float* qr = qfb + (size_t)(tn0+tA)*64;
        fB0 = *(const float4*)(qr+ks8);    fB1 = *(const float4*)(qr+ks8+4);
        fB2 = *(const float4*)(qr+32+ks8); fB3 = *(const float4*)(qr+32+ks8+4);
      }
    } else if (lane < 16) {
      // issue c+1 v/lr loads (land during serial B)
      float vvn[16], lrn[16];
      #pragma unroll
      for (int t=0;t<CH_;++t){
        vvn[t] = vfb[(size_t)(tn0+t)*64 + e0 + lane];
        lrn[t] = lrp[(size_t)(tn0+t)*16];
      }
      // ---- serial 16 tokens ----
      float2 c13[CH_];
      float* sop = sob + (size_t)t0*(H_*HD_) + lane;
      #pragma unroll
      for (int t = 0; t < CH_; ++t) {
        float gk[16], gq[16];
        #pragma unroll
        for (int si=0; si<4; ++si){
          if (si*4 < t){
            float4 a = *(const float4*)&GKK[t*16+si*4];
            gk[si*4]=a.x; gk[si*4+1]=a.y; gk[si*4+2]=a.z; gk[si*4+3]=a.w;
          }
          if (si*4 <= t){
            float4 a = *(const float4*)&GQK[t*16+si*4];
            gq[si*4]=a.x; gq[si*4+1]=a.y; gq[si*4+2]=a.z; gq[si*4+3]=a.w;
          }
        }
        float h1 = KW1[t*16+lane], h3 = KW3[t*16+lane];
        #pragma unroll
        for (int s = 0; s < t; ++s) {
          h1 = fmaf(-gk[s], c13[s].x, h1);
          h3 = fmaf(-gk[s], c13[s].y, h3);
        }
        const float sg = 1.0f/(1.0f + __expf(-h1));
        const float s1 = h1*sg;
        const float er = fmaf(s1, h3, -vvr[t]);
        const float ds = sg*fmaf(h1, 1.0f - sg, 1.0f);
        const float lt = lrr[t];
        float2 cc; cc.x = lt*(er*h3*ds); cc.y = lt*(er*s1);
        c13[t] = cc;
        *(float2*)&C13[(t*16+lane)*2] = cc;
        float o1 = QW1[t*16+lane], o3 = QW3[t*16+lane];
        #pragma unroll
        for (int s = 0; s <= t; ++s) {
          o1 = fmaf(-gq[s], c13[s].x, o1);
          o3 = fmaf(-gq[s], c13[s].y, o3);
        }
        sop[(size_t)t*(H_*HD_)] = (o1/(1.0f + __expf(-o1)))*o3;
      }
      // rotate prefetched v/lr into live arrays (loads completed during B)
      #pragma unroll
      for (int t=0;t<CH_;++t){ vvr[t]=vvn[t]; lrr[t]=lrn[t]; }
    }
    __syncthreads();   // bar2: C13 visible

    // ---- phase C: rank-16 W update (k rows L1-hot from prefetch) + mirror ----
    #pragma unroll
    for (int s = 0; s < CH_; ++s) {
      const float2 cc = *(const float2*)&C13[(s*16+we)*2];
      const float4 ks = *(const float4*)(kfb + (size_t)(t0+s)*64 + wd);
      w1r[0] = fmaf(-ks.x, cc.x, w1r[0]); w1r[1] = fmaf(-ks.y, cc.x, w1r[1]);
      w1r[2] = fmaf(-ks.z, cc.x, w1r[2]); w1r[3] = fmaf(-ks.w, cc.x, w1r[3]);
      w3r[0] = fmaf(-ks.x, cc.y, w3r[0]); w3r[1] = fmaf(-ks.y, cc.y, w3r[1]);
      w3r[2] = fmaf(-ks.z, cc.y, w3r[2]); w3r[3] = fmaf(-ks.w, cc.y, w3r[3]);
    }
    write_mirrors();
    __syncthreads();   // bar3: mirror ready for A(c+1)
  }
}

// ---------------- grouped RMSNorm * norm_w * sigmoid(gate) -> bf16 y ----------------
__global__ void k_norm_gate(const float* __restrict__ so, const float* __restrict__ gate,
                            const float* __restrict__ nw, __hip_bfloat16* __restrict__ y)
{
  int idx = blockIdx.x*4 + (threadIdx.x>>6);  // (b*N+t)*16+h
  int e = threadIdx.x & 63;
  float o = so[(size_t)idx*64 + e];
  float ss = o*o;
  #pragma unroll
  for (int m=32; m>=1; m>>=1) ss += __shfl_xor(ss, m, 64);
  float rms = rsqrtf(ss*(1.0f/64.0f) + 1e-6f);
  int hh = idx & 15;
  size_t bn = (size_t)(idx >> 4);
  int d = hh*64 + e;
  float g = gate[bn*1024 + d];
  float val = o*rms*nw[d] * (1.0f/(1.0f+__expf(-g)));
  y[bn*1024 + d] = __float2bfloat16(val);
}

extern "C" void kernel_launch(void* const* d_in, const int* in_sizes, int n_in,
                              void* d_out, int out_size, void* d_ws, size_t ws_size,
                              hipStream_t stream)
{
  const float* x   = (const float*)d_in[0];
  const float* Wq  = (const float*)d_in[1];
  const float* Wk  = (const float*)d_in[2];
  const float* Wv  = (const float*)d_in[3];
  const float* Wo  = (const float*)d_in[4];
  const float* w1i = (const float*)d_in[5];
  const float* w3i = (const float*)d_in[6];
  const float* Wlr = (const float*)d_in[7];
  const float* nw  = (const float*)d_in[8];
  const float* Wg1 = (const float*)d_in[9];
  const float* Wg2 = (const float*)d_in[10];
  float* out = (float*)d_out;

  char* p = (char*)d_ws;
  auto take = [&](size_t bytes)->void*{ void* r = (void*)p; p += (bytes + 255) & ~(size_t)255; return r; };
  __hip_bfloat16* xb   = (__hip_bfloat16*)take((size_t)MTOT*D_*2);
  __hip_bfloat16* Wqt  = (__hip_bfloat16*)take((size_t)D_*D_*2);
  __hip_bfloat16* Wkt  = (__hip_bfloat16*)take((size_t)D_*D_*2);
  __hip_bfloat16* Wvt  = (__hip_bfloat16*)take((size_t)D_*D_*2);
  __hip_bfloat16* Wot  = (__hip_bfloat16*)take((size_t)D_*D_*2);
  __hip_bfloat16* Wg2t = (__hip_bfloat16*)take((size_t)D_*HD_*2);
  __hip_bfloat16* t1b  = (__hip_bfloat16*)take((size_t)MTOT*HD_*2);
  float* qf  = (float*)take((size_t)MTOT*D_*4);
  float* kf  = (float*)take((size_t)MTOT*D_*4);
  float* vf  = (float*)take((size_t)MTOT*D_*4);
  float* lrb = (float*)take((size_t)MTOT*H_*4);
  float* sob = (float*)take((size_t)MTOT*D_*4);
  __hip_bfloat16* yb = (__hip_bfloat16*)take((size_t)MTOT*D_*2);

  k_cast_bf16<<<MTOT*D_/4/256, 256, 0, stream>>>(x, xb, MTOT*D_/4);
  k_transpose_cast<<<dim3(16,16), 256, 0, stream>>>(Wq, Wqt, D_, D_);
  k_transpose_cast<<<dim3(16,16), 256, 0, stream>>>(Wk, Wkt, D_, D_);
  k_transpose_cast<<<dim3(16,16), 256, 0, stream>>>(Wv, Wvt, D_, D_);
  k_transpose_cast<<<dim3(16,16), 256, 0, stream>>>(Wo, Wot, D_, D_);
  k_transpose_cast<<<dim3(16,1),  256, 0, stream>>>(Wg2, Wg2t, HD_, D_);
  k_small_proj<<<MTOT, 256, 0, stream>>>(x, Wg1, Wlr, t1b, lrb);
  // q,k,v projections (silu on q,k), scattered to [b][h][t][e]
  k_gemm_bt<1,1><<<dim3(8,64), 256, 0, stream>>>(xb, Wqt, qf, MTOT, D_, D_);
  k_gemm_bt<1,1><<<dim3(8,64), 256, 0, stream>>>(xb, Wkt, kf, MTOT, D_, D_);
  k_gemm_bt<0,1><<<dim3(8,64), 256, 0, stream>>>(xb, Wvt, vf, MTOT, D_, D_);
  // gate pre-activation into d_out (free scratch until final GEMM)
  k_gemm_bt<0,0><<<dim3(8,64), 256, 0, stream>>>(t1b, Wg2t, out, MTOT, D_, HD_);
  k_scan6<<<256, 256, 0, stream>>>(qf, kf, vf, lrb, w1i, w3i, sob);
  k_norm_gate<<<MTOT*H_/4, 256, 0, stream>>>(sob, out, nw, yb);
  k_gemm_bt<0,0><<<dim3(8,64), 256, 0, stream>>>(yb, Wot, out, MTOT, D_, D_);
}

// Round 7
// 754.668 us; speedup vs baseline: 4.2020x; 1.2250x over previous
//
#include <hip/hip_runtime.h>
#include <hip/hip_bf16.h>

#define B_ 4
#define N_ 2048
#define D_ 1024
#define H_ 16
#define HD_ 64
#define MTOT (B_*N_)   // 8192
#define CH_ 16         // scan chunk size
#define NCH_ (N_/CH_)  // 128

typedef __attribute__((ext_vector_type(8))) short short8v;
typedef __attribute__((ext_vector_type(4))) float f32x4;

// ---------------- cast x -> bf16 (vectorized) ----------------
__global__ void k_cast_bf16(const float* __restrict__ in, __hip_bfloat16* __restrict__ out, int n4){
  int i = blockIdx.x*256 + threadIdx.x;
  if (i >= n4) return;
  float4 vv = ((const float4*)in)[i];
  __hip_bfloat16 b0 = __float2bfloat16(vv.x), b1 = __float2bfloat16(vv.y),
                 b2 = __float2bfloat16(vv.z), b3 = __float2bfloat16(vv.w);
  ushort4 o;
  o.x = *(const unsigned short*)&b0; o.y = *(const unsigned short*)&b1;
  o.z = *(const unsigned short*)&b2; o.w = *(const unsigned short*)&b3;
  ((ushort4*)out)[i] = o;
}

// ---------------- transpose + cast: out[c][r] = in[r][c] ----------------
__global__ void k_transpose_cast(const float* __restrict__ in, __hip_bfloat16* __restrict__ out,
                                 int R, int C){
  __shared__ float tile[64][65];
  int r0 = blockIdx.y*64, c0 = blockIdx.x*64;
  int tid = threadIdx.x;
  #pragma unroll
  for (int i=0;i<16;i++){ int idx = tid + i*256; int rr = idx>>6, cc = idx&63;
    tile[rr][cc] = in[(size_t)(r0+rr)*C + (c0+cc)]; }
  __syncthreads();
  #pragma unroll
  for (int i=0;i<16;i++){ int idx = tid + i*256; int rr = idx>>6, cc = idx&63;
    out[(size_t)(c0+rr)*R + (r0+cc)] = __float2bfloat16(tile[cc][rr]); }
}

// ---------------- pack gate/lr weights: WgL[128][1024] = [Wg1^T ; Wlr^T ; 0] ----------------
__global__ void k_prep_wgl(const float* __restrict__ Wg1, const float* __restrict__ Wlr,
                           __hip_bfloat16* __restrict__ WgL){
  int idx = blockIdx.x*256 + threadIdx.x;   // 0..131071
  int r = idx >> 10, d = idx & 1023;
  float v = 0.f;
  if (r < 64) v = Wg1[(size_t)d*64 + r];
  else if (r < 80) v = Wlr[(size_t)d*16 + (r-64)];
  WgL[idx] = __float2bfloat16(v);
}

// ---------------- post: proj[8192][128] -> t1 bf16 (cols 0-63), lr = 0.01*sigmoid (cols 64-79) ----
__global__ void k_post_gl(const float* __restrict__ proj, __hip_bfloat16* __restrict__ t1,
                          float* __restrict__ lrout){
  int m = blockIdx.x*4 + (threadIdx.x>>6);
  int e = threadIdx.x & 63;
  float val = proj[(size_t)m*128 + e];
  t1[(size_t)m*64 + e] = __float2bfloat16(val);
  if (e < 16){
    float s = proj[(size_t)m*128 + 64 + e];
    lrout[(size_t)m*16 + e] = 0.01f/(1.0f+__expf(-s));
  }
}

// ---------------- async global->LDS helper (16B per lane, dest = base + lane*16) ----------------
__device__ __forceinline__ void gl2lds16(const void* g, void* l){
  __builtin_amdgcn_global_load_lds((const __attribute__((address_space(1))) void*)g,
                                   (__attribute__((address_space(3))) void*)l, 16, 0, 0);
}

// ---------------- bf16 MFMA GEMM with global_load_lds staging ----------------
// C = act(A @ BT^T), A:(M,K) BT:(N,K) bf16, C fp32.
// ACT: 0 none, 1 silu.  LAYOUT: 0 -> C[m*N+col]; 1 -> C[((b*16+h)*2048+t)*64+e] scatter (q/k/v)
// LDS linear [128][32] (no pad: required by global_load_lds); 2 barriers/K-step (m97 structure).
template<int ACT, int LAYOUT>
__global__ __launch_bounds__(256,2) void k_gemm_bt2(
    const __hip_bfloat16* __restrict__ A, const __hip_bfloat16* __restrict__ BT,
    float* __restrict__ C, int M, int N, int K)
{
  __shared__ short As[128*32];
  __shared__ short Bs[128*32];
  const int n0 = blockIdx.x*128, m0 = blockIdx.y*128;
  const int tid = threadIdx.x, lane = tid & 63, wid = tid >> 6;
  const int wm = wid >> 1, wn = wid & 1;
  const short* Aps = (const short*)A;
  const short* Bps = (const short*)BT;
  f32x4 acc[4][4] = {};
  // staging: wave wid covers rows [32*wid, 32*wid+32) of A-tile and B-tile.
  // each global_load_lds: 16 rows x 32 cols (1KB), lane i -> row +(i>>2), colseg (i&3)*8.
  const int srow = wid*32 + (lane>>2);
  const int scol = (lane&3)*8;
  const size_t aoff0 = (size_t)(m0+srow)*K + scol;
  const size_t boff0 = (size_t)(n0+srow)*K + scol;
  short* lA = As + wid*1024;   // row wid*32, 16 rows = 512 elems per chunk
  short* lB = Bs + wid*1024;
  const int row = lane & 15, kq = (lane >> 4)*8;
  for (int kk = 0; kk < K; kk += 32) {
    __syncthreads();   // previous iteration's frag reads complete before overwrite
    gl2lds16(Aps + aoff0 + kk,                 lA);
    gl2lds16(Aps + aoff0 + (size_t)16*K + kk,  lA + 512);
    gl2lds16(Bps + boff0 + kk,                 lB);
    gl2lds16(Bps + boff0 + (size_t)16*K + kk,  lB + 512);
    __syncthreads();   // vmcnt(0) drained before barrier -> tile visible
    short8v af[4], bfr[4];
    #pragma unroll
    for (int i=0;i<4;i++) af[i]  = *(const short8v*)(As + (wm*64 + i*16 + row)*32 + kq);
    #pragma unroll
    for (int j=0;j<4;j++) bfr[j] = *(const short8v*)(Bs + (wn*64 + j*16 + row)*32 + kq);
    #pragma unroll
    for (int i=0;i<4;i++)
      #pragma unroll
      for (int j=0;j<4;j++)
        acc[i][j] = __builtin_amdgcn_mfma_f32_16x16x32_bf16(af[i], bfr[j], acc[i][j], 0, 0, 0);
  }
  #pragma unroll
  for (int i=0;i<4;i++){
    #pragma unroll
    for (int j=0;j<4;j++){
      int col = n0 + wn*64 + j*16 + (lane & 15);
      #pragma unroll
      for (int qq=0; qq<4; ++qq){
        int rowg = m0 + wm*64 + i*16 + (lane>>4)*4 + qq;
        float val = acc[i][j][qq];
        if (ACT==1) val = val/(1.0f+__expf(-val));
        if (LAYOUT==0) {
          C[(size_t)rowg*N + col] = val;
        } else {
          size_t oidx = ((((size_t)(rowg>>11))*16 + (col>>6))*(size_t)N_ + (size_t)(rowg & 2047))*64
                        + (size_t)(col & 63);
          C[oidx] = val;
        }
      }
    }
  }
}

// ---------------- helpers for chunked scan ----------------
__device__ __forceinline__ unsigned short bfr16(float x){
  __hip_bfloat16 b = __float2bfloat16(x);
  return *(unsigned short*)&b;
}
// convert two float4 (8 contiguous fp32) into a bf16 MFMA fragment
__device__ __forceinline__ short8v cvt_frag(const float4 a, const float4 c){
  short8v r;
  r[0]=(short)bfr16(a.x); r[1]=(short)bfr16(a.y); r[2]=(short)bfr16(a.z); r[3]=(short)bfr16(a.w);
  r[4]=(short)bfr16(c.x); r[5]=(short)bfr16(c.y); r[6]=(short)bfr16(c.z); r[7]=(short)bfr16(c.w);
  return r;
}

// ---------------- chunked fast-weight scan, latency-hidden schedule ----------------
__global__ __launch_bounds__(256,1) void k_scan6(
    const float* __restrict__ q, const float* __restrict__ k, const float* __restrict__ v,
    const float* __restrict__ lr, const float* __restrict__ w1i, const float* __restrict__ w3i,
    float* __restrict__ so)
{
  const int blk = blockIdx.x;            // 0..255
  const int bh  = blk >> 2;              // b*16+h
  const int sl  = blk & 3;               // e-slab
  const int b = bh >> 4, h = bh & 15;
  const int e0 = sl*16;
  const int tid = threadIdx.x, lane = tid & 63, wid = tid >> 6;
  const int tA = lane & 15, ks8 = (lane >> 4)*8;

  __shared__ __align__(16) __hip_bfloat16 Wb1[16*64];   // mirror [e][d], XOR-swizzled
  __shared__ __align__(16) __hip_bfloat16 Wb3[16*64];
  __shared__ __align__(16) float KW1[256], KW3[256], QW1[256], QW3[256];  // [t][e]
  __shared__ __align__(16) float GKK[256], GQK[256];    // [t][s]
  __shared__ __align__(16) float C13[16*16*2];          // [s][e][{c1,c3}]

  // W master: thread owns (e = tid&15 within slab, rows wd..wd+3)
  const int we = tid & 15;
  const int wd = (tid >> 4) * 4;
  float w1r[4], w3r[4];
  {
    const float* w1p = w1i + (size_t)h*HD_*HD_ + e0 + we;
    const float* w3p = w3i + (size_t)h*HD_*HD_ + e0 + we;
    #pragma unroll
    for (int j=0;j<4;j++){ w1r[j] = w1p[(size_t)(wd+j)*64]; w3r[j] = w3p[(size_t)(wd+j)*64]; }
  }
  const int mir_off = we*128 + ((wd*2) ^ ((we&7)<<4));  // byte offset, 8B aligned
  auto write_mirrors = [&](){
    uint2 p1, p3;
    p1.x = (unsigned)bfr16(w1r[0]) | ((unsigned)bfr16(w1r[1])<<16);
    p1.y = (unsigned)bfr16(w1r[2]) | ((unsigned)bfr16(w1r[3])<<16);
    p3.x = (unsigned)bfr16(w3r[0]) | ((unsigned)bfr16(w3r[1])<<16);
    p3.y = (unsigned)bfr16(w3r[2]) | ((unsigned)bfr16(w3r[3])<<16);
    *(uint2*)((char*)Wb1 + mir_off) = p1;
    *(uint2*)((char*)Wb3 + mir_off) = p3;
  };
  write_mirrors();

  const float* kfb = k + (size_t)bh*N_*64;
  const float* qfb = q + (size_t)bh*N_*64;
  const float* vfb = v + (size_t)bh*N_*64;
  const float* lrp = lr + ((size_t)b*N_)*16 + h;
  float* sob = so + (((size_t)b*N_)*16 + h)*64 + e0;

  auto mir_read = [&](const __hip_bfloat16* Wm, int m)->short8v{
    return *(const short8v*)((const char*)Wm + tA*128 + (((m*32+ks8)*2) ^ ((tA&7)<<4)));
  };

  float4 fA0,fA1,fA2,fA3;          // wave1: k frags; wave2: q frags; wave3: k frags
  float4 fB0,fB1,fB2,fB3;          // wave3: q frags
  float  vvr[16], lrr[16];         // wave0 lanes<16

  if (wid >= 1) {
    const float* xr = ((wid==2) ? qfb : kfb) + (size_t)tA*64;
    fA0 = *(const float4*)(xr+ks8);    fA1 = *(const float4*)(xr+ks8+4);
    fA2 = *(const float4*)(xr+32+ks8); fA3 = *(const float4*)(xr+32+ks8+4);
    if (wid==3){
      const float* qr = qfb + (size_t)tA*64;
      fB0 = *(const float4*)(qr+ks8);    fB1 = *(const float4*)(qr+ks8+4);
      fB2 = *(const float4*)(qr+32+ks8); fB3 = *(const float4*)(qr+32+ks8+4);
    }
  } else if (lane < 16) {
    #pragma unroll
    for (int t=0;t<CH_;++t){
      vvr[t] = vfb[(size_t)t*64 + e0 + lane];
      lrr[t] = lrp[(size_t)t*16];
    }
  }
  __syncthreads();

  #pragma unroll 1
  for (int c = 0; c < NCH_; ++c) {
    const int t0 = c*CH_;

    // ---- phase A: MFMA products from prefetched regs (waves 1-3) ----
    if (wid >= 1) {
      short8v af0 = cvt_frag(fA0,fA1), af1 = cvt_frag(fA2,fA3);
      if (wid <= 2) {
        float* d0 = (wid==1) ? KW1 : QW1;
        float* d1 = (wid==1) ? KW3 : QW3;
        f32x4 acc = {};
        acc = __builtin_amdgcn_mfma_f32_16x16x32_bf16(af0, mir_read(Wb1,0), acc, 0,0,0);
        acc = __builtin_amdgcn_mfma_f32_16x16x32_bf16(af1, mir_read(Wb1,1), acc, 0,0,0);
        #pragma unroll
        for (int qq=0;qq<4;++qq) d0[((lane>>4)*4+qq)*16 + tA] = acc[qq];
        f32x4 ac3 = {};
        ac3 = __builtin_amdgcn_mfma_f32_16x16x32_bf16(af0, mir_read(Wb3,0), ac3, 0,0,0);
        ac3 = __builtin_amdgcn_mfma_f32_16x16x32_bf16(af1, mir_read(Wb3,1), ac3, 0,0,0);
        #pragma unroll
        for (int qq=0;qq<4;++qq) d1[((lane>>4)*4+qq)*16 + tA] = ac3[qq];
      } else {
        short8v aq0 = cvt_frag(fB0,fB1), aq1 = cvt_frag(fB2,fB3);
        f32x4 acc = {};
        acc = __builtin_amdgcn_mfma_f32_16x16x32_bf16(af0, af0, acc, 0,0,0);
        acc = __builtin_amdgcn_mfma_f32_16x16x32_bf16(af1, af1, acc, 0,0,0);
        #pragma unroll
        for (int qq=0;qq<4;++qq) GKK[((lane>>4)*4+qq)*16 + tA] = acc[qq];
        f32x4 ac2 = {};
        ac2 = __builtin_amdgcn_mfma_f32_16x16x32_bf16(aq0, af0, ac2, 0,0,0);
        ac2 = __builtin_amdgcn_mfma_f32_16x16x32_bf16(aq1, af1, ac2, 0,0,0);
        #pragma unroll
        for (int qq=0;qq<4;++qq) GQK[((lane>>4)*4+qq)*16 + tA] = ac2[qq];
      }
    }
    __syncthreads();   // bar1: A results visible

    // ---- phase B window ----
    const int tn0 = ((c+1 < NCH_) ? c+1 : c) * CH_;
    if (wid >= 1) {
      const float* xr = ((wid==2) ? qfb : kfb) + (size_t)(tn0+tA)*64;
      fA0 = *(const float4*)(xr+ks8);    fA1 = *(const float4*)(xr+ks8+4);
      fA2 = *(const float4*)(xr+32+ks8); fA3 = *(const float4*)(xr+32+ks8+4);
      if (wid==3){
        const float* qr = qfb + (size_t)(tn0+tA)*64;
        fB0 = *(const float4*)(qr+ks8);    fB1 = *(const float4*)(qr+ks8+4);
        fB2 = *(const float4*)(qr+32+ks8); fB3 = *(const float4*)(qr+32+ks8+4);
      }
    } else if (lane < 16) {
      float vvn[16], lrn[16];
      #pragma unroll
      for (int t=0;t<CH_;++t){
        vvn[t] = vfb[(size_t)(tn0+t)*64 + e0 + lane];
        lrn[t] = lrp[(size_t)(tn0+t)*16];
      }
      float2 c13[CH_];
      float* sop = sob + (size_t)t0*(H_*HD_) + lane;
      #pragma unroll
      for (int t = 0; t < CH_; ++t) {
        float gk[16], gq[16];
        #pragma unroll
        for (int si=0; si<4; ++si){
          if (si*4 < t){
            float4 a = *(const float4*)&GKK[t*16+si*4];
            gk[si*4]=a.x; gk[si*4+1]=a.y; gk[si*4+2]=a.z; gk[si*4+3]=a.w;
          }
          if (si*4 <= t){
            float4 a = *(const float4*)&GQK[t*16+si*4];
            gq[si*4]=a.x; gq[si*4+1]=a.y; gq[si*4+2]=a.z; gq[si*4+3]=a.w;
          }
        }
        float h1 = KW1[t*16+lane], h3 = KW3[t*16+lane];
        #pragma unroll
        for (int s = 0; s < t; ++s) {
          h1 = fmaf(-gk[s], c13[s].x, h1);
          h3 = fmaf(-gk[s], c13[s].y, h3);
        }
        const float sg = 1.0f/(1.0f + __expf(-h1));
        const float s1 = h1*sg;
        const float er = fmaf(s1, h3, -vvr[t]);
        const float ds = sg*fmaf(h1, 1.0f - sg, 1.0f);
        const float lt = lrr[t];
        float2 cc; cc.x = lt*(er*h3*ds); cc.y = lt*(er*s1);
        c13[t] = cc;
        *(float2*)&C13[(t*16+lane)*2] = cc;
        float o1 = QW1[t*16+lane], o3 = QW3[t*16+lane];
        #pragma unroll
        for (int s = 0; s <= t; ++s) {
          o1 = fmaf(-gq[s], c13[s].x, o1);
          o3 = fmaf(-gq[s], c13[s].y, o3);
        }
        sop[(size_t)t*(H_*HD_)] = (o1/(1.0f + __expf(-o1)))*o3;
      }
      #pragma unroll
      for (int t=0;t<CH_;++t){ vvr[t]=vvn[t]; lrr[t]=lrn[t]; }
    }
    __syncthreads();   // bar2: C13 visible

    // ---- phase C: rank-16 W update (k rows L1-hot) + mirror ----
    #pragma unroll
    for (int s = 0; s < CH_; ++s) {
      const float2 cc = *(const float2*)&C13[(s*16+we)*2];
      const float4 ks = *(const float4*)(kfb + (size_t)(t0+s)*64 + wd);
      w1r[0] = fmaf(-ks.x, cc.x, w1r[0]); w1r[1] = fmaf(-ks.y, cc.x, w1r[1]);
      w1r[2] = fmaf(-ks.z, cc.x, w1r[2]); w1r[3] = fmaf(-ks.w, cc.x, w1r[3]);
      w3r[0] = fmaf(-ks.x, cc.y, w3r[0]); w3r[1] = fmaf(-ks.y, cc.y, w3r[1]);
      w3r[2] = fmaf(-ks.z, cc.y, w3r[2]); w3r[3] = fmaf(-ks.w, cc.y, w3r[3]);
    }
    write_mirrors();
    __syncthreads();   // bar3: mirror ready for A(c+1)
  }
}

// ---------------- grouped RMSNorm * norm_w * sigmoid(gate) -> bf16 y ----------------
__global__ void k_norm_gate(const float* __restrict__ so, const float* __restrict__ gate,
                            const float* __restrict__ nw, __hip_bfloat16* __restrict__ y)
{
  int idx = blockIdx.x*4 + (threadIdx.x>>6);  // (b*N+t)*16+h
  int e = threadIdx.x & 63;
  float o = so[(size_t)idx*64 + e];
  float ss = o*o;
  #pragma unroll
  for (int m=32; m>=1; m>>=1) ss += __shfl_xor(ss, m, 64);
  float rms = rsqrtf(ss*(1.0f/64.0f) + 1e-6f);
  int hh = idx & 15;
  size_t bn = (size_t)(idx >> 4);
  int d = hh*64 + e;
  float g = gate[bn*1024 + d];
  float val = o*rms*nw[d] * (1.0f/(1.0f+__expf(-g)));
  y[bn*1024 + d] = __float2bfloat16(val);
}

extern "C" void kernel_launch(void* const* d_in, const int* in_sizes, int n_in,
                              void* d_out, int out_size, void* d_ws, size_t ws_size,
                              hipStream_t stream)
{
  const float* x   = (const float*)d_in[0];
  const float* Wq  = (const float*)d_in[1];
  const float* Wk  = (const float*)d_in[2];
  const float* Wv  = (const float*)d_in[3];
  const float* Wo  = (const float*)d_in[4];
  const float* w1i = (const float*)d_in[5];
  const float* w3i = (const float*)d_in[6];
  const float* Wlr = (const float*)d_in[7];
  const float* nw  = (const float*)d_in[8];
  const float* Wg1 = (const float*)d_in[9];
  const float* Wg2 = (const float*)d_in[10];
  float* out = (float*)d_out;

  char* p = (char*)d_ws;
  auto take = [&](size_t bytes)->void*{ void* r = (void*)p; p += (bytes + 255) & ~(size_t)255; return r; };
  __hip_bfloat16* xb   = (__hip_bfloat16*)take((size_t)MTOT*D_*2);
  __hip_bfloat16* Wqt  = (__hip_bfloat16*)take((size_t)D_*D_*2);
  __hip_bfloat16* Wkt  = (__hip_bfloat16*)take((size_t)D_*D_*2);
  __hip_bfloat16* Wvt  = (__hip_bfloat16*)take((size_t)D_*D_*2);
  __hip_bfloat16* Wot  = (__hip_bfloat16*)take((size_t)D_*D_*2);
  __hip_bfloat16* Wg2t = (__hip_bfloat16*)take((size_t)D_*HD_*2);
  __hip_bfloat16* WgL  = (__hip_bfloat16*)take((size_t)128*D_*2);
  __hip_bfloat16* t1b  = (__hip_bfloat16*)take((size_t)MTOT*HD_*2);
  float* projt = (float*)take((size_t)MTOT*128*4);
  float* qf  = (float*)take((size_t)MTOT*D_*4);
  float* kf  = (float*)take((size_t)MTOT*D_*4);
  float* vf  = (float*)take((size_t)MTOT*D_*4);
  float* lrb = (float*)take((size_t)MTOT*H_*4);
  float* sob = (float*)take((size_t)MTOT*D_*4);
  __hip_bfloat16* yb = (__hip_bfloat16*)take((size_t)MTOT*D_*2);

  k_cast_bf16<<<MTOT*D_/4/256, 256, 0, stream>>>(x, xb, MTOT*D_/4);
  k_transpose_cast<<<dim3(16,16), 256, 0, stream>>>(Wq, Wqt, D_, D_);
  k_transpose_cast<<<dim3(16,16), 256, 0, stream>>>(Wk, Wkt, D_, D_);
  k_transpose_cast<<<dim3(16,16), 256, 0, stream>>>(Wv, Wvt, D_, D_);
  k_transpose_cast<<<dim3(16,16), 256, 0, stream>>>(Wo, Wot, D_, D_);
  k_transpose_cast<<<dim3(16,1),  256, 0, stream>>>(Wg2, Wg2t, HD_, D_);
  k_prep_wgl<<<512, 256, 0, stream>>>(Wg1, Wlr, WgL);
  // gate bottleneck + lr head in one GEMM: proj = x @ [Wg1 | Wlr | 0]
  k_gemm_bt2<0,0><<<dim3(1,64), 256, 0, stream>>>(xb, WgL, projt, MTOT, 128, D_);
  k_post_gl<<<MTOT/4, 256, 0, stream>>>(projt, t1b, lrb);
  // q,k,v projections (silu on q,k), scattered to [b][h][t][e]
  k_gemm_bt2<1,1><<<dim3(8,64), 256, 0, stream>>>(xb, Wqt, qf, MTOT, D_, D_);
  k_gemm_bt2<1,1><<<dim3(8,64), 256, 0, stream>>>(xb, Wkt, kf, MTOT, D_, D_);
  k_gemm_bt2<0,1><<<dim3(8,64), 256, 0, stream>>>(xb, Wvt, vf, MTOT, D_, D_);
  // gate pre-activation into d_out (free scratch until final GEMM)
  k_gemm_bt2<0,0><<<dim3(8,64), 256, 0, stream>>>(t1b, Wg2t, out, MTOT, D_, HD_);
  k_scan6<<<256, 256, 0, stream>>>(qf, kf, vf, lrb, w1i, w3i, sob);
  k_norm_gate<<<MTOT*H_/4, 256, 0, stream>>>(sob, out, nw, yb);
  k_gemm_bt2<0,0><<<dim3(8,64), 256, 0, stream>>>(yb, Wot, out, MTOT, D_, D_);
}

// Round 8
// 605.872 us; speedup vs baseline: 5.2339x; 1.2456x over previous
//
#include <hip/hip_runtime.h>
#include <hip/hip_bf16.h>

#define B_ 4
#define N_ 2048
#define D_ 1024
#define H_ 16
#define HD_ 64
#define MTOT (B_*N_)   // 8192
#define CH_ 16         // scan chunk size
#define NCH_ (N_/CH_)  // 128

typedef __attribute__((ext_vector_type(8))) short short8v;
typedef __attribute__((ext_vector_type(4))) float f32x4;

// ---------------- cast x -> bf16 (vectorized) ----------------
__global__ void k_cast_bf16(const float* __restrict__ in, __hip_bfloat16* __restrict__ out, int n4){
  int i = blockIdx.x*256 + threadIdx.x;
  if (i >= n4) return;
  float4 vv = ((const float4*)in)[i];
  __hip_bfloat16 b0 = __float2bfloat16(vv.x), b1 = __float2bfloat16(vv.y),
                 b2 = __float2bfloat16(vv.z), b3 = __float2bfloat16(vv.w);
  ushort4 o;
  o.x = *(const unsigned short*)&b0; o.y = *(const unsigned short*)&b1;
  o.z = *(const unsigned short*)&b2; o.w = *(const unsigned short*)&b3;
  ((ushort4*)out)[i] = o;
}

// ---------------- transpose + cast: out[c][r] = in[r][c] ----------------
__global__ void k_transpose_cast(const float* __restrict__ in, __hip_bfloat16* __restrict__ out,
                                 int R, int C){
  __shared__ float tile[64][65];
  int r0 = blockIdx.y*64, c0 = blockIdx.x*64;
  int tid = threadIdx.x;
  #pragma unroll
  for (int i=0;i<16;i++){ int idx = tid + i*256; int rr = idx>>6, cc = idx&63;
    tile[rr][cc] = in[(size_t)(r0+rr)*C + (c0+cc)]; }
  __syncthreads();
  #pragma unroll
  for (int i=0;i<16;i++){ int idx = tid + i*256; int rr = idx>>6, cc = idx&63;
    out[(size_t)(c0+rr)*R + (r0+cc)] = __float2bfloat16(tile[cc][rr]); }
}

// ---------------- pack gate/lr weights: WgL[128][1024] = [Wg1^T ; Wlr^T ; 0] ----------------
__global__ void k_prep_wgl(const float* __restrict__ Wg1, const float* __restrict__ Wlr,
                           __hip_bfloat16* __restrict__ WgL){
  int idx = blockIdx.x*256 + threadIdx.x;   // 0..131071
  int r = idx >> 10, d = idx & 1023;
  float v = 0.f;
  if (r < 64) v = Wg1[(size_t)d*64 + r];
  else if (r < 80) v = Wlr[(size_t)d*16 + (r-64)];
  WgL[idx] = __float2bfloat16(v);
}

// ---------------- post: proj[8192][128] -> t1 bf16 (cols 0-63), lr = 0.01*sigmoid (cols 64-79) ----
__global__ void k_post_gl(const float* __restrict__ proj, __hip_bfloat16* __restrict__ t1,
                          float* __restrict__ lrout){
  int m = blockIdx.x*4 + (threadIdx.x>>6);
  int e = threadIdx.x & 63;
  float val = proj[(size_t)m*128 + e];
  t1[(size_t)m*64 + e] = __float2bfloat16(val);
  if (e < 16){
    float s = proj[(size_t)m*128 + 64 + e];
    lrout[(size_t)m*16 + e] = 0.01f/(1.0f+__expf(-s));
  }
}

// ---------------- async global->LDS helper (16B per lane, dest = base + lane*16) ----------------
__device__ __forceinline__ void gl2lds16(const void* g, void* l){
  __builtin_amdgcn_global_load_lds((const __attribute__((address_space(1))) void*)g,
                                   (__attribute__((address_space(3))) void*)l, 16, 0, 0);
}

// ---------------- bf16 MFMA GEMM with global_load_lds staging ----------------
template<int ACT, int LAYOUT>
__global__ __launch_bounds__(256,2) void k_gemm_bt2(
    const __hip_bfloat16* __restrict__ A, const __hip_bfloat16* __restrict__ BT,
    float* __restrict__ C, int M, int N, int K)
{
  __shared__ short As[128*32];
  __shared__ short Bs[128*32];
  const int n0 = blockIdx.x*128, m0 = blockIdx.y*128;
  const int tid = threadIdx.x, lane = tid & 63, wid = tid >> 6;
  const int wm = wid >> 1, wn = wid & 1;
  const short* Aps = (const short*)A;
  const short* Bps = (const short*)BT;
  f32x4 acc[4][4] = {};
  const int srow = wid*32 + (lane>>2);
  const int scol = (lane&3)*8;
  const size_t aoff0 = (size_t)(m0+srow)*K + scol;
  const size_t boff0 = (size_t)(n0+srow)*K + scol;
  short* lA = As + wid*1024;
  short* lB = Bs + wid*1024;
  const int row = lane & 15, kq = (lane >> 4)*8;
  for (int kk = 0; kk < K; kk += 32) {
    __syncthreads();
    gl2lds16(Aps + aoff0 + kk,                 lA);
    gl2lds16(Aps + aoff0 + (size_t)16*K + kk,  lA + 512);
    gl2lds16(Bps + boff0 + kk,                 lB);
    gl2lds16(Bps + boff0 + (size_t)16*K + kk,  lB + 512);
    __syncthreads();
    short8v af[4], bfr[4];
    #pragma unroll
    for (int i=0;i<4;i++) af[i]  = *(const short8v*)(As + (wm*64 + i*16 + row)*32 + kq);
    #pragma unroll
    for (int j=0;j<4;j++) bfr[j] = *(const short8v*)(Bs + (wn*64 + j*16 + row)*32 + kq);
    #pragma unroll
    for (int i=0;i<4;i++)
      #pragma unroll
      for (int j=0;j<4;j++)
        acc[i][j] = __builtin_amdgcn_mfma_f32_16x16x32_bf16(af[i], bfr[j], acc[i][j], 0, 0, 0);
  }
  #pragma unroll
  for (int i=0;i<4;i++){
    #pragma unroll
    for (int j=0;j<4;j++){
      int col = n0 + wn*64 + j*16 + (lane & 15);
      #pragma unroll
      for (int qq=0; qq<4; ++qq){
        int rowg = m0 + wm*64 + i*16 + (lane>>4)*4 + qq;
        float val = acc[i][j][qq];
        if (ACT==1) val = val/(1.0f+__expf(-val));
        if (LAYOUT==0) {
          C[(size_t)rowg*N + col] = val;
        } else {
          size_t oidx = ((((size_t)(rowg>>11))*16 + (col>>6))*(size_t)N_ + (size_t)(rowg & 2047))*64
                        + (size_t)(col & 63);
          C[oidx] = val;
        }
      }
    }
  }
}

// ---------------- helpers for chunked scan ----------------
__device__ __forceinline__ unsigned short bfr16(float x){
  __hip_bfloat16 b = __float2bfloat16(x);
  return *(unsigned short*)&b;
}
__device__ __forceinline__ short8v cvt_frag(const float4 a, const float4 c){
  short8v r;
  r[0]=(short)bfr16(a.x); r[1]=(short)bfr16(a.y); r[2]=(short)bfr16(a.z); r[3]=(short)bfr16(a.w);
  r[4]=(short)bfr16(c.x); r[5]=(short)bfr16(c.y); r[6]=(short)bfr16(c.z); r[7]=(short)bfr16(c.w);
  return r;
}

// ---------------- chunked fast-weight scan v7 ----------------
// Phase A (waves1-3): MFMA products. KW1/KW3 stored e-major [e][t] (float4);
// QW1/QW3 t-major [t][e]; Gram [t][s]. Phase B (wave0, 16 lanes): serial c13 only —
// KW rows preloaded to regs, gk rows pipelined 3 tokens ahead in registers; no o-corr.
// Phase O (all 256 thr): o[t][e] = QW - sum GQK*c13, output store. Phase C: rank-16 update.
__global__ __launch_bounds__(256,1) void k_scan7(
    const float* __restrict__ q, const float* __restrict__ k, const float* __restrict__ v,
    const float* __restrict__ lr, const float* __restrict__ w1i, const float* __restrict__ w3i,
    float* __restrict__ so)
{
  const int blk = blockIdx.x;            // 0..255
  const int bh  = blk >> 2;              // b*16+h
  const int sl  = blk & 3;               // e-slab
  const int b = bh >> 4, h = bh & 15;
  const int e0 = sl*16;
  const int tid = threadIdx.x, lane = tid & 63, wid = tid >> 6;
  const int tA = lane & 15, ks8 = (lane >> 4)*8;

  __shared__ __align__(16) __hip_bfloat16 Wb1[16*64];   // mirror [e][d], XOR-swizzled
  __shared__ __align__(16) __hip_bfloat16 Wb3[16*64];
  __shared__ __align__(16) float KW1e[256], KW3e[256];  // [e][t]
  __shared__ __align__(16) float QW1[256], QW3[256];    // [t][e]
  __shared__ __align__(16) float GKK[256], GQK[256];    // [t][s]
  __shared__ __align__(16) float C13[512];              // [s][e][{c1,c3}]

  const int we = tid & 15;
  const int wd = (tid >> 4) * 4;
  float w1r[4], w3r[4];
  {
    const float* w1p = w1i + (size_t)h*HD_*HD_ + e0 + we;
    const float* w3p = w3i + (size_t)h*HD_*HD_ + e0 + we;
    #pragma unroll
    for (int j=0;j<4;j++){ w1r[j] = w1p[(size_t)(wd+j)*64]; w3r[j] = w3p[(size_t)(wd+j)*64]; }
  }
  const int mir_off = we*128 + ((wd*2) ^ ((we&7)<<4));  // byte offset, 8B aligned
  auto write_mirrors = [&](){
    uint2 p1, p3;
    p1.x = (unsigned)bfr16(w1r[0]) | ((unsigned)bfr16(w1r[1])<<16);
    p1.y = (unsigned)bfr16(w1r[2]) | ((unsigned)bfr16(w1r[3])<<16);
    p3.x = (unsigned)bfr16(w3r[0]) | ((unsigned)bfr16(w3r[1])<<16);
    p3.y = (unsigned)bfr16(w3r[2]) | ((unsigned)bfr16(w3r[3])<<16);
    *(uint2*)((char*)Wb1 + mir_off) = p1;
    *(uint2*)((char*)Wb3 + mir_off) = p3;
  };
  write_mirrors();

  const float* kfb = k + (size_t)bh*N_*64;
  const float* qfb = q + (size_t)bh*N_*64;
  const float* vfb = v + (size_t)bh*N_*64;
  const float* lrp = lr + ((size_t)b*N_)*16 + h;
  float* sob = so + (((size_t)b*N_)*16 + h)*64 + e0;

  auto mir_read = [&](const __hip_bfloat16* Wm, int m)->short8v{
    return *(const short8v*)((const char*)Wm + tA*128 + (((m*32+ks8)*2) ^ ((tA&7)<<4)));
  };

  float4 fA0,fA1,fA2,fA3;          // wave1: k frags; wave2: q frags; wave3: k frags
  float4 fB0,fB1,fB2,fB3;          // wave3: q frags
  float  vvr[16], lrr[16];         // wave0 lanes<16

  if (wid >= 1) {
    const float* xr = ((wid==2) ? qfb : kfb) + (size_t)tA*64;
    fA0 = *(const float4*)(xr+ks8);    fA1 = *(const float4*)(xr+ks8+4);
    fA2 = *(const float4*)(xr+32+ks8); fA3 = *(const float4*)(xr+32+ks8+4);
    if (wid==3){
      const float* qr = qfb + (size_t)tA*64;
      fB0 = *(const float4*)(qr+ks8);    fB1 = *(const float4*)(qr+ks8+4);
      fB2 = *(const float4*)(qr+32+ks8); fB3 = *(const float4*)(qr+32+ks8+4);
    }
  } else if (lane < 16) {
    #pragma unroll
    for (int t=0;t<CH_;++t){
      vvr[t] = vfb[(size_t)t*64 + e0 + lane];
      lrr[t] = lrp[(size_t)t*16];
    }
  }
  __syncthreads();

  #pragma unroll 1
  for (int c = 0; c < NCH_; ++c) {
    const int t0 = c*CH_;

    // ---- phase A: MFMA products from prefetched regs (waves 1-3) ----
    if (wid == 1) {
      short8v af0 = cvt_frag(fA0,fA1), af1 = cvt_frag(fA2,fA3);
      f32x4 acc = {};
      acc = __builtin_amdgcn_mfma_f32_16x16x32_bf16(af0, mir_read(Wb1,0), acc, 0,0,0);
      acc = __builtin_amdgcn_mfma_f32_16x16x32_bf16(af1, mir_read(Wb1,1), acc, 0,0,0);
      *(f32x4*)&KW1e[tA*16 + (lane>>4)*4] = acc;          // e-major
      f32x4 ac3 = {};
      ac3 = __builtin_amdgcn_mfma_f32_16x16x32_bf16(af0, mir_read(Wb3,0), ac3, 0,0,0);
      ac3 = __builtin_amdgcn_mfma_f32_16x16x32_bf16(af1, mir_read(Wb3,1), ac3, 0,0,0);
      *(f32x4*)&KW3e[tA*16 + (lane>>4)*4] = ac3;
    } else if (wid == 2) {
      short8v af0 = cvt_frag(fA0,fA1), af1 = cvt_frag(fA2,fA3);
      f32x4 acc = {};
      acc = __builtin_amdgcn_mfma_f32_16x16x32_bf16(af0, mir_read(Wb1,0), acc, 0,0,0);
      acc = __builtin_amdgcn_mfma_f32_16x16x32_bf16(af1, mir_read(Wb1,1), acc, 0,0,0);
      #pragma unroll
      for (int qq=0;qq<4;++qq) QW1[((lane>>4)*4+qq)*16 + tA] = acc[qq];   // t-major
      f32x4 ac3 = {};
      ac3 = __builtin_amdgcn_mfma_f32_16x16x32_bf16(af0, mir_read(Wb3,0), ac3, 0,0,0);
      ac3 = __builtin_amdgcn_mfma_f32_16x16x32_bf16(af1, mir_read(Wb3,1), ac3, 0,0,0);
      #pragma unroll
      for (int qq=0;qq<4;++qq) QW3[((lane>>4)*4+qq)*16 + tA] = ac3[qq];
    } else if (wid == 3) {
      short8v af0 = cvt_frag(fA0,fA1), af1 = cvt_frag(fA2,fA3);
      short8v aq0 = cvt_frag(fB0,fB1), aq1 = cvt_frag(fB2,fB3);
      f32x4 acc = {};
      acc = __builtin_amdgcn_mfma_f32_16x16x32_bf16(af0, af0, acc, 0,0,0);
      acc = __builtin_amdgcn_mfma_f32_16x16x32_bf16(af1, af1, acc, 0,0,0);
      #pragma unroll
      for (int qq=0;qq<4;++qq) GKK[((lane>>4)*4+qq)*16 + tA] = acc[qq];
      f32x4 ac2 = {};
      ac2 = __builtin_amdgcn_mfma_f32_16x16x32_bf16(aq0, af0, ac2, 0,0,0);
      ac2 = __builtin_amdgcn_mfma_f32_16x16x32_bf16(aq1, af1, ac2, 0,0,0);
      #pragma unroll
      for (int qq=0;qq<4;++qq) GQK[((lane>>4)*4+qq)*16 + tA] = ac2[qq];
    }
    __syncthreads();   // bar1: A results visible

    // ---- phase B window ----
    const int tn0 = ((c+1 < NCH_) ? c+1 : c) * CH_;
    if (wid >= 1) {
      // issue chunk c+1 prefetch; park at bar2 while loads fly under wave0's B
      const float* xr = ((wid==2) ? qfb : kfb) + (size_t)(tn0+tA)*64;
      fA0 = *(const float4*)(xr+ks8);    fA1 = *(const float4*)(xr+ks8+4);
      fA2 = *(const float4*)(xr+32+ks8); fA3 = *(const float4*)(xr+32+ks8+4);
      if (wid==3){
        const float* qr = qfb + (size_t)(tn0+tA)*64;
        fB0 = *(const float4*)(qr+ks8);    fB1 = *(const float4*)(qr+ks8+4);
        fB2 = *(const float4*)(qr+32+ks8); fB3 = *(const float4*)(qr+32+ks8+4);
      }
    } else if (lane < 16) {
      // issue c+1 v/lr loads (land during serial B)
      float vvn[16], lrn[16];
      #pragma unroll
      for (int t=0;t<CH_;++t){
        vvn[t] = vfb[(size_t)(tn0+t)*64 + e0 + lane];
        lrn[t] = lrp[(size_t)(tn0+t)*16];
      }
      // preload this lane's KW rows (e = lane) into scalars
      float kw1s[16], kw3s[16];
      #pragma unroll
      for (int i2=0;i2<4;i2++){
        f32x4 a1 = *(const f32x4*)&KW1e[lane*16 + i2*4];
        f32x4 a3 = *(const f32x4*)&KW3e[lane*16 + i2*4];
        kw1s[i2*4+0]=a1[0]; kw1s[i2*4+1]=a1[1]; kw1s[i2*4+2]=a1[2]; kw1s[i2*4+3]=a1[3];
        kw3s[i2*4+0]=a3[0]; kw3s[i2*4+1]=a3[1]; kw3s[i2*4+2]=a3[2]; kw3s[i2*4+3]=a3[3];
      }
      // gram gk rows: rotating 3-deep register pipeline (row t lives in grow[t%3])
      f32x4 grow[3][4];
      #pragma unroll
      for (int i2=0;i2<4;i2++){
        grow[1][i2] = *(const f32x4*)&GKK[16 + i2*4];
        grow[2][i2] = *(const f32x4*)&GKK[32 + i2*4];
      }
      float2 c13r[CH_];
      #pragma unroll
      for (int t = 0; t < CH_; ++t) {
        float h1 = kw1s[t], h3 = kw3s[t];
        #pragma unroll
        for (int s = 0; s < t; ++s) {
          const float g = grow[t%3][s>>2][s&3];
          h1 = fmaf(-g, c13r[s].x, h1);
          h3 = fmaf(-g, c13r[s].y, h3);
        }
        if (t + 3 < CH_) {   // refill consumed slot with row t+3 (lands 3 tokens later)
          #pragma unroll
          for (int i2=0;i2<4;i2++) grow[(t+3)%3][i2] = *(const f32x4*)&GKK[(t+3)*16 + i2*4];
        }
        const float sg = 1.0f/(1.0f + __expf(-h1));
        const float s1 = h1*sg;
        const float er = fmaf(s1, h3, -vvr[t]);
        const float ds = sg*fmaf(h1, 1.0f - sg, 1.0f);
        const float lt = lrr[t];
        float2 cc; cc.x = lt*(er*h3*ds); cc.y = lt*(er*s1);
        c13r[t] = cc;
        *(float2*)&C13[(t*16+lane)*2] = cc;
      }
      #pragma unroll
      for (int t=0;t<CH_;++t){ vvr[t]=vvn[t]; lrr[t]=lrn[t]; }
    }
    __syncthreads();   // bar2: C13 visible

    // ---- phase O: all 256 threads, one (t,e) each: outputs via deferred corr ----
    {
      const int ot = tid >> 4, oe = tid & 15;
      float o1 = QW1[ot*16+oe], o3 = QW3[ot*16+oe];
      for (int s = 0; s <= ot; ++s) {
        const float g = GQK[ot*16+s];
        const float2 cc = *(const float2*)&C13[(s*16+oe)*2];
        o1 = fmaf(-g, cc.x, o1);
        o3 = fmaf(-g, cc.y, o3);
      }
      sob[(size_t)(t0+ot)*(H_*HD_) + oe] = (o1/(1.0f + __expf(-o1)))*o3;
    }

    // ---- phase C: rank-16 W update + rewrite mirror ----
    #pragma unroll
    for (int s = 0; s < CH_; ++s) {
      const float2 cc = *(const float2*)&C13[(s*16+we)*2];
      const float4 ks = *(const float4*)(kfb + (size_t)(t0+s)*64 + wd);
      w1r[0] = fmaf(-ks.x, cc.x, w1r[0]); w1r[1] = fmaf(-ks.y, cc.x, w1r[1]);
      w1r[2] = fmaf(-ks.z, cc.x, w1r[2]); w1r[3] = fmaf(-ks.w, cc.x, w1r[3]);
      w3r[0] = fmaf(-ks.x, cc.y, w3r[0]); w3r[1] = fmaf(-ks.y, cc.y, w3r[1]);
      w3r[2] = fmaf(-ks.z, cc.y, w3r[2]); w3r[3] = fmaf(-ks.w, cc.y, w3r[3]);
    }
    write_mirrors();
    __syncthreads();   // bar3: mirror ready for A(c+1)
  }
}

// ---------------- grouped RMSNorm * norm_w * sigmoid(gate) -> bf16 y ----------------
__global__ void k_norm_gate(const float* __restrict__ so, const float* __restrict__ gate,
                            const float* __restrict__ nw, __hip_bfloat16* __restrict__ y)
{
  int idx = blockIdx.x*4 + (threadIdx.x>>6);  // (b*N+t)*16+h
  int e = threadIdx.x & 63;
  float o = so[(size_t)idx*64 + e];
  float ss = o*o;
  #pragma unroll
  for (int m=32; m>=1; m>>=1) ss += __shfl_xor(ss, m, 64);
  float rms = rsqrtf(ss*(1.0f/64.0f) + 1e-6f);
  int hh = idx & 15;
  size_t bn = (size_t)(idx >> 4);
  int d = hh*64 + e;
  float g = gate[bn*1024 + d];
  float val = o*rms*nw[d] * (1.0f/(1.0f+__expf(-g)));
  y[bn*1024 + d] = __float2bfloat16(val);
}

extern "C" void kernel_launch(void* const* d_in, const int* in_sizes, int n_in,
                              void* d_out, int out_size, void* d_ws, size_t ws_size,
                              hipStream_t stream)
{
  const float* x   = (const float*)d_in[0];
  const float* Wq  = (const float*)d_in[1];
  const float* Wk  = (const float*)d_in[2];
  const float* Wv  = (const float*)d_in[3];
  const float* Wo  = (const float*)d_in[4];
  const float* w1i = (const float*)d_in[5];
  const float* w3i = (const float*)d_in[6];
  const float* Wlr = (const float*)d_in[7];
  const float* nw  = (const float*)d_in[8];
  const float* Wg1 = (const float*)d_in[9];
  const float* Wg2 = (const float*)d_in[10];
  float* out = (float*)d_out;

  char* p = (char*)d_ws;
  auto take = [&](size_t bytes)->void*{ void* r = (void*)p; p += (bytes + 255) & ~(size_t)255; return r; };
  __hip_bfloat16* xb   = (__hip_bfloat16*)take((size_t)MTOT*D_*2);
  __hip_bfloat16* Wqt  = (__hip_bfloat16*)take((size_t)D_*D_*2);
  __hip_bfloat16* Wkt  = (__hip_bfloat16*)take((size_t)D_*D_*2);
  __hip_bfloat16* Wvt  = (__hip_bfloat16*)take((size_t)D_*D_*2);
  __hip_bfloat16* Wot  = (__hip_bfloat16*)take((size_t)D_*D_*2);
  __hip_bfloat16* Wg2t = (__hip_bfloat16*)take((size_t)D_*HD_*2);
  __hip_bfloat16* WgL  = (__hip_bfloat16*)take((size_t)128*D_*2);
  __hip_bfloat16* t1b  = (__hip_bfloat16*)take((size_t)MTOT*HD_*2);
  float* projt = (float*)take((size_t)MTOT*128*4);
  float* qf  = (float*)take((size_t)MTOT*D_*4);
  float* kf  = (float*)take((size_t)MTOT*D_*4);
  float* vf  = (float*)take((size_t)MTOT*D_*4);
  float* lrb = (float*)take((size_t)MTOT*H_*4);
  float* sob = (float*)take((size_t)MTOT*D_*4);
  __hip_bfloat16* yb = (__hip_bfloat16*)take((size_t)MTOT*D_*2);

  k_cast_bf16<<<MTOT*D_/4/256, 256, 0, stream>>>(x, xb, MTOT*D_/4);
  k_transpose_cast<<<dim3(16,16), 256, 0, stream>>>(Wq, Wqt, D_, D_);
  k_transpose_cast<<<dim3(16,16), 256, 0, stream>>>(Wk, Wkt, D_, D_);
  k_transpose_cast<<<dim3(16,16), 256, 0, stream>>>(Wv, Wvt, D_, D_);
  k_transpose_cast<<<dim3(16,16), 256, 0, stream>>>(Wo, Wot, D_, D_);
  k_transpose_cast<<<dim3(16,1),  256, 0, stream>>>(Wg2, Wg2t, HD_, D_);
  k_prep_wgl<<<512, 256, 0, stream>>>(Wg1, Wlr, WgL);
  // gate bottleneck + lr head in one GEMM: proj = x @ [Wg1 | Wlr | 0]
  k_gemm_bt2<0,0><<<dim3(1,64), 256, 0, stream>>>(xb, WgL, projt, MTOT, 128, D_);
  k_post_gl<<<MTOT/4, 256, 0, stream>>>(projt, t1b, lrb);
  // q,k,v projections (silu on q,k), scattered to [b][h][t][e]
  k_gemm_bt2<1,1><<<dim3(8,64), 256, 0, stream>>>(xb, Wqt, qf, MTOT, D_, D_);
  k_gemm_bt2<1,1><<<dim3(8,64), 256, 0, stream>>>(xb, Wkt, kf, MTOT, D_, D_);
  k_gemm_bt2<0,1><<<dim3(8,64), 256, 0, stream>>>(xb, Wvt, vf, MTOT, D_, D_);
  // gate pre-activation into d_out (free scratch until final GEMM)
  k_gemm_bt2<0,0><<<dim3(8,64), 256, 0, stream>>>(t1b, Wg2t, out, MTOT, D_, HD_);
  k_scan7<<<256, 256, 0, stream>>>(qf, kf, vf, lrb, w1i, w3i, sob);
  k_norm_gate<<<MTOT*H_/4, 256, 0, stream>>>(sob, out, nw, yb);
  k_gemm_bt2<0,0><<<dim3(8,64), 256, 0, stream>>>(yb, Wot, out, MTOT, D_, D_);
}